// Round 3
// baseline (1236.632 us; speedup 1.0000x reference)
//
#include <hip/hip_runtime.h>
#include <hip/hip_bf16.h>
#include <hip/hip_fp16.h>

#define N_NODES_C 100000
#define N_EDGES_C 500000
#define N_REL_C 6
#define IN_DIM_C 64
#define HID_C 128
#define HEADS_C 4
#define CPH_C 32
#define N_GRAPHS_C 1024
#define NBLK_SCAN 391   // ceil(100000/256)
#define SH_PAD 8        // LDS transpose row pad (halves): 2-way banks, 16B aligned

typedef _Float16 f16x8 __attribute__((ext_vector_type(8)));
typedef float f32x4 __attribute__((ext_vector_type(4)));

// ========== CSR hist+rank, fused with fp32->fp16 converts + logit-weight prep ==========
__global__ __launch_bounds__(256) void hist_rank_convert_kernel(
    const int* __restrict__ ei, int* __restrict__ cnt, int* __restrict__ rank,
    const float* __restrict__ x, __half* __restrict__ xh,
    const float* __restrict__ W1, const float* __restrict__ W2,
    __half* __restrict__ Wt1, __half* __restrict__ Wt2,
    const float* __restrict__ as1, const float* __restrict__ ad1,
    float* __restrict__ wsd, float* __restrict__ wdd) {
    int i = blockIdx.x * 256 + threadIdx.x;
    // convert x (1.6M float4 groups)
    if (i < N_NODES_C * IN_DIM_C / 4) {
        float4 v = ((const float4*)x)[i];
        union { __half h[4]; uint2 u; } u;
        u.h[0] = __float2half(v.x); u.h[1] = __float2half(v.y);
        u.h[2] = __float2half(v.z); u.h[3] = __float2half(v.w);
        ((uint2*)xh)[i] = u.u;
    }
    // convert + transpose W1, W2  (Wt layout: [r][n][k])
    if (i < N_REL_C * IN_DIM_C * HID_C) {
        int r = i / (IN_DIM_C * HID_C);
        int rem = i - r * (IN_DIM_C * HID_C);
        int k = rem / HID_C, n = rem - k * HID_C;
        Wt1[(size_t)r * HID_C * IN_DIM_C + n * IN_DIM_C + k] = __float2half(W1[i]);
    }
    if (i < N_REL_C * HID_C * HID_C) {
        int r = i / (HID_C * HID_C);
        int rem = i - r * (HID_C * HID_C);
        int k = rem / HID_C, n = rem - k * HID_C;
        Wt2[(size_t)r * HID_C * HID_C + n * HID_C + k] = __float2half(W2[i]);
    }
    // layer-1 logit weight vectors: wsd[r][h][k] = sum_c W1[r][k][h*32+c]*as1[r][h][c]
    if (i < N_REL_C * HEADS_C * IN_DIM_C) {   // 1536
        int r = i >> 8, h = (i >> 6) & 3, k = i & 63;
        const float* wrow = W1 + ((size_t)(r * IN_DIM_C + k)) * HID_C + h * CPH_C;
        const float* av_s = as1 + (r * HEADS_C + h) * CPH_C;
        const float* av_d = ad1 + (r * HEADS_C + h) * CPH_C;
        float ss = 0.f, sd = 0.f;
#pragma unroll
        for (int c = 0; c < CPH_C; c++) {
            ss = fmaf(wrow[c], av_s[c], ss);
            sd = fmaf(wrow[c], av_d[c], sd);
        }
        wsd[i] = ss; wdd[i] = sd;
    }
    // histogram + per-edge rank
    if (i < N_REL_C * N_EDGES_C) {
        int r = i / N_EDGES_C;
        int e = i - r * N_EDGES_C;
        int dst = ei[(size_t)r * 2 * N_EDGES_C + N_EDGES_C + e];
        rank[i] = atomicAdd(&cnt[r * N_NODES_C + dst], 1);
    }
}

// per-256-block exclusive scan; bsums[r][b] = block total
__global__ __launch_bounds__(256) void scan1_kernel(const int* __restrict__ cnt,
                                                    int* __restrict__ rowptr,
                                                    int* __restrict__ blocksums) {
    int r = blockIdx.y, b = blockIdx.x, t = threadIdx.x;
    int idx = b * 256 + t;
    int v = (idx < N_NODES_C) ? cnt[r * N_NODES_C + idx] : 0;
    int orig = v;
    int lane = t & 63, w = t >> 6;
#pragma unroll
    for (int off = 1; off < 64; off <<= 1) {
        int n = __shfl_up(v, off);
        if (lane >= off) v += n;
    }
    __shared__ int wt[4];
    if (lane == 63) wt[w] = v;
    __syncthreads();
    int add = 0;
    for (int i = 0; i < w; i++) add += wt[i];
    v += add;
    if (idx < N_NODES_C) rowptr[(size_t)r * (N_NODES_C + 1) + idx] = v - orig;
    if (t == 255) blocksums[r * NBLK_SCAN + b] = v;
}

// scan block sums -> exclusive prefixes (final rowptr = rowptrP + bsums[b])
__global__ __launch_bounds__(512) void scan2_kernel(int* __restrict__ blocksums) {
    int r = blockIdx.x, t = threadIdx.x;
    int v = (t < NBLK_SCAN) ? blocksums[r * NBLK_SCAN + t] : 0;
    int orig = v;
    int lane = t & 63, w = t >> 6;
#pragma unroll
    for (int off = 1; off < 64; off <<= 1) {
        int n = __shfl_up(v, off);
        if (lane >= off) v += n;
    }
    __shared__ int wt[8];
    if (lane == 63) wt[w] = v;
    __syncthreads();
    int add = 0;
    for (int i = 0; i < w; i++) add += wt[i];
    v += add;
    if (t < NBLK_SCAN) blocksums[r * NBLK_SCAN + t] = v - orig;
}

// atomic-free scatter; final rowptr computed inline
__global__ __launch_bounds__(256) void scatter_kernel(const int* __restrict__ ei,
                                                      const int* __restrict__ rowptrP,
                                                      const int* __restrict__ bsums,
                                                      const int* __restrict__ rank,
                                                      int* __restrict__ srcids) {
    int i = blockIdx.x * 256 + threadIdx.x;
    if (i >= N_REL_C * N_EDGES_C) return;
    int r = i / N_EDGES_C;
    int e = i - r * N_EDGES_C;
    int src = ei[(size_t)r * 2 * N_EDGES_C + e];
    int dst = ei[(size_t)r * 2 * N_EDGES_C + N_EDGES_C + e];
    int base = rowptrP[(size_t)r * (N_NODES_C + 1) + dst] + bsums[r * NBLK_SCAN + (dst >> 8)];
    srcids[(size_t)r * N_EDGES_C + base + rank[i]] = src;
}

// ========== layer-1 logits: als1[r][n][h] = xh[n] . wsd[r][h], ald likewise ==========
__global__ __launch_bounds__(256) void logit1_kernel(
    const __half* __restrict__ xh, const float* __restrict__ wsd,
    const float* __restrict__ wdd, float* __restrict__ als, float* __restrict__ ald) {
    int wave = threadIdx.x >> 6, lane = threadIdx.x & 63;
    int node = blockIdx.x * 4 + wave;
    __shared__ float sx[4][IN_DIM_C];
    if (lane < 32) {
        float2 f = __half22float2(*(const __half2*)(xh + (size_t)node * IN_DIM_C + lane * 2));
        sx[wave][lane * 2] = f.x;
        sx[wave][lane * 2 + 1] = f.y;
    }
    __syncthreads();
    if (lane < 48) {
        int r = lane >> 3, rem = lane & 7;
        int h = rem >> 1, sd = rem & 1;
        const float* wp = (sd ? wdd : wsd) + (size_t)(r * HEADS_C + h) * IN_DIM_C;
        float acc = 0.f;
#pragma unroll
        for (int k = 0; k < IN_DIM_C; k += 4) {
            float4 wv = *(const float4*)(wp + k);
            acc = fmaf(sx[wave][k], wv.x, acc);
            acc = fmaf(sx[wave][k + 1], wv.y, acc);
            acc = fmaf(sx[wave][k + 2], wv.z, acc);
            acc = fmaf(sx[wave][k + 3], wv.w, acc);
        }
        float* dst = sd ? ald : als;
        dst[((size_t)r * N_NODES_C + node) * HEADS_C + h] = acc;
    }
}

// ========== layer-1 fused: BARRIER-FREE per-wave gather + MFMA + LN ==========
// Each wave owns 4 nodes (grp = one node). Edge walk: srcids batch-loaded 16-ahead
// into a register, broadcast per-edge via __shfl (srcid load off the critical chain).
// Softmax inverse folded into S before MFMA; A rows = head*4+node (16 valid rows);
// all 8 col-tiles accumulated, lane keeps only its head's 2 tiles at epilogue.
// Same-wave LDS transpose => ZERO __syncthreads in the whole kernel.
__global__ __launch_bounds__(256) void agg1_kernel(
    const int* __restrict__ rowptrP, const int* __restrict__ bsums,
    const int* __restrict__ srcids, const __half* __restrict__ xh,
    const float* __restrict__ als, const float* __restrict__ ald,
    const __half* __restrict__ Wt1, const float* __restrict__ bias,
    const float* __restrict__ g, const float* __restrict__ be,
    __half* __restrict__ Cbh) {
    __shared__ __align__(16) _Float16 S[4][16][72];    // per-wave A staging (rows=h*4+n)
    __shared__ __align__(16) _Float16 E[4][4][136];    // per-wave epilogue row assembly
    const int wave = threadIdx.x >> 6, lane = threadIdx.x & 63;
    const int grp = lane >> 4, j16 = lane & 15;        // gather roles
    const int quad = grp, m = j16;                     // MFMA roles (same bits)
    const int grpbase = lane & 48;
    const int nbase = blockIdx.x * 16 + wave * 4;
    const int node = nbase + grp;

    f32x4 acc[8];
#pragma unroll
    for (int t = 0; t < 8; t++) acc[t] = (f32x4){0.f, 0.f, 0.f, 0.f};

    for (int r = 0; r < N_REL_C; r++) {
        const int* rp = rowptrP + (size_t)r * (N_NODES_C + 1);
        const int* bs = bsums + r * NBLK_SCAN;
        const int* sp = srcids + (size_t)r * N_EDGES_C;
        const float* alr = als + (size_t)r * N_NODES_C * HEADS_C;
        const float* adr = ald + (size_t)r * N_NODES_C * HEADS_C;

        float adv0, adv1, adv2, adv3;
        {
            float4 t4 = *(const float4*)(adr + (size_t)node * HEADS_C);
            adv0 = t4.x; adv1 = t4.y; adv2 = t4.z; adv3 = t4.w;
        }
        int s = rp[node] + bs[node >> 8];
        int e = (node == N_NODES_C - 1) ? N_EDGES_C : rp[node + 1] + bs[(node + 1) >> 8];

        float racc[4][4];
#pragma unroll
        for (int h = 0; h < 4; h++)
#pragma unroll
            for (int j = 0; j < 4; j++) racc[h][j] = 0.f;
        float rden[4] = {0.f, 0.f, 0.f, 0.f};

        for (int base = s; base < e; base += 16) {
            int bidx = base + j16;
            int bsrc = sp[(bidx < e) ? bidx : (e - 1)];   // 16 srcids batched per node
            int cl = e - base; if (cl > 16) cl = 16;
            int src = __shfl(bsrc, grpbase);
            uint2 xw = *(const uint2*)(xh + (size_t)src * IN_DIM_C + j16 * 4);
            float4 lg = *(const float4*)(alr + (size_t)src * HEADS_C);
            for (int idx = 0; idx < cl; idx++) {
                int nn = (idx + 1 < cl) ? idx + 1 : idx;
                int nsrc = __shfl(bsrc, grpbase + nn);
                uint2 nxw = *(const uint2*)(xh + (size_t)nsrc * IN_DIM_C + j16 * 4);
                float4 nlg = *(const float4*)(alr + (size_t)nsrc * HEADS_C);
                float v0 = lg.x + adv0; v0 = fmaxf(v0, 0.2f * v0); float ex0 = __expf(v0);
                float v1 = lg.y + adv1; v1 = fmaxf(v1, 0.2f * v1); float ex1 = __expf(v1);
                float v2 = lg.z + adv2; v2 = fmaxf(v2, 0.2f * v2); float ex2 = __expf(v2);
                float v3 = lg.w + adv3; v3 = fmaxf(v3, 0.2f * v3); float ex3 = __expf(v3);
                rden[0] += ex0; rden[1] += ex1; rden[2] += ex2; rden[3] += ex3;
                union { uint2 u; _Float16 hh[4]; } xu;
                xu.u = xw;
                float xf0 = (float)xu.hh[0], xf1 = (float)xu.hh[1];
                float xf2 = (float)xu.hh[2], xf3 = (float)xu.hh[3];
                racc[0][0] = fmaf(xf0, ex0, racc[0][0]); racc[0][1] = fmaf(xf1, ex0, racc[0][1]);
                racc[0][2] = fmaf(xf2, ex0, racc[0][2]); racc[0][3] = fmaf(xf3, ex0, racc[0][3]);
                racc[1][0] = fmaf(xf0, ex1, racc[1][0]); racc[1][1] = fmaf(xf1, ex1, racc[1][1]);
                racc[1][2] = fmaf(xf2, ex1, racc[1][2]); racc[1][3] = fmaf(xf3, ex1, racc[1][3]);
                racc[2][0] = fmaf(xf0, ex2, racc[2][0]); racc[2][1] = fmaf(xf1, ex2, racc[2][1]);
                racc[2][2] = fmaf(xf2, ex2, racc[2][2]); racc[2][3] = fmaf(xf3, ex2, racc[2][3]);
                racc[3][0] = fmaf(xf0, ex3, racc[3][0]); racc[3][1] = fmaf(xf1, ex3, racc[3][1]);
                racc[3][2] = fmaf(xf2, ex3, racc[3][2]); racc[3][3] = fmaf(xf3, ex3, racc[3][3]);
                xw = nxw; lg = nlg;
            }
        }

        // fold softmax inverse into S (fp16), rows = h*4 + node-in-wave
#pragma unroll
        for (int h = 0; h < 4; h++) {
            float iv = 1.f / (rden[h] + 1e-16f);
            __half2 p0 = __float22half2_rn(make_float2(racc[h][0] * iv, racc[h][1] * iv));
            __half2 p1 = __float22half2_rn(make_float2(racc[h][2] * iv, racc[h][3] * iv));
            *(__half2*)&S[wave][h * 4 + grp][j16 * 4] = p0;
            *(__half2*)&S[wave][h * 4 + grp][j16 * 4 + 2] = p1;
        }

        // per-wave MFMA: C[row=quad*4+i][col=t*16+m], accumulate all 8 col-tiles
        const __half* Wr = Wt1 + (size_t)r * HID_C * IN_DIM_C;
#pragma unroll
        for (int kc = 0; kc < 2; kc++) {
            f16x8 a = *(const f16x8*)&S[wave][m][kc * 32 + quad * 8];
#pragma unroll
            for (int t = 0; t < 8; t++) {
                f16x8 b = *(const f16x8*)(Wr + (size_t)(t * 16 + m) * IN_DIM_C + kc * 32 + quad * 8);
                acc[t] = __builtin_amdgcn_mfma_f32_16x16x32_f16(a, b, acc[t], 0, 0, 0);
            }
        }
    }

    // select this lane's two useful tiles (compile-time t, runtime compare: no scratch)
    f32x4 selA = (f32x4){0.f, 0.f, 0.f, 0.f}, selB = selA;
#pragma unroll
    for (int t = 0; t < 8; t++) {
        if (quad == (t >> 1)) {
            if ((t & 1) == 0) selA = acc[t];
            else selB = acc[t];
        }
    }

    // epilogue: bias + softsign + LN (wave-wide shuffles), assemble rows in LDS, vec-store
    const int c0 = quad * 32 + m, c1 = c0 + 16;
    float bs0 = 0.f, bs1 = 0.f;
#pragma unroll
    for (int r = 0; r < N_REL_C; r++) {
        bs0 += bias[r * HID_C + c0];
        bs1 += bias[r * HID_C + c1];
    }
    float gv0 = g[c0], gv1 = g[c1], bv0 = be[c0], bv1 = be[c1];
#pragma unroll
    for (int n = 0; n < 4; n++) {
        float v0 = selA[n] + bs0; v0 = v0 / (1.f + fabsf(v0));
        float v1 = selB[n] + bs1; v1 = v1 / (1.f + fabsf(v1));
        float sum = v0 + v1, sq = v0 * v0 + v1 * v1;
#pragma unroll
        for (int off = 1; off < 64; off <<= 1) {
            sum += __shfl_xor(sum, off);
            sq += __shfl_xor(sq, off);
        }
        float mu = sum * (1.f / 128.f);
        float var = sq * (1.f / 128.f) - mu * mu;
        float ivn = rsqrtf(var + 1e-5f);
        E[wave][n][c0] = (_Float16)((v0 - mu) * ivn * gv0 + bv0);
        E[wave][n][c1] = (_Float16)((v1 - mu) * ivn * gv1 + bv1);
    }
    {
        int nn = lane >> 4, mm = lane & 15;
        *(uint4*)(Cbh + (size_t)(nbase + nn) * HID_C + mm * 8) = *(const uint4*)&E[wave][nn][mm * 8];
    }
}

// ================= fp16 MFMA GEMM + attn-logit epilogue (layer 2) =================
template <int K>
__global__ __launch_bounds__(256) void gemm_mfma_kernel(
    const __half* __restrict__ Xh, const __half* __restrict__ Wtbase,
    __half* __restrict__ Hbase,
    const float* __restrict__ asbase, const float* __restrict__ adbase,
    float* __restrict__ alsbase, float* __restrict__ aldbase) {
    __shared__ _Float16 sh[4][16][HID_C + SH_PAD];
    const int slot = blockIdx.y;
    const __half* Wt = Wtbase + (size_t)slot * HID_C * K;
    __half* H = Hbase + (size_t)slot * N_NODES_C * HID_C;
    const int wave = threadIdx.x >> 6, lane = threadIdx.x & 63;
    const int r0 = blockIdx.x * 64 + wave * 16;
    const int m = lane & 15, quad = lane >> 4;
    int arow = r0 + m;
    if (arow > N_NODES_C - 1) arow = N_NODES_C - 1;
    const __half* ap = Xh + (size_t)arow * K + quad * 8;
    const __half* bp = Wt + (size_t)m * K + quad * 8;

    f32x4 acc[8];
#pragma unroll
    for (int t = 0; t < 8; t++) acc[t] = (f32x4){0.f, 0.f, 0.f, 0.f};

#pragma unroll
    for (int kc = 0; kc < K; kc += 32) {
        f16x8 a = *(const f16x8*)(ap + kc);
#pragma unroll
        for (int t = 0; t < 8; t++) {
            f16x8 b = *(const f16x8*)(bp + (size_t)t * 16 * K + kc);
            acc[t] = __builtin_amdgcn_mfma_f32_16x16x32_f16(a, b, acc[t], 0, 0, 0);
        }
    }

    // transpose C-layout -> row-major via LDS (same-wave: no barrier needed)
#pragma unroll
    for (int t = 0; t < 8; t++)
#pragma unroll
        for (int i = 0; i < 4; i++)
            sh[wave][quad * 4 + i][t * 16 + m] = (_Float16)acc[t][i];
#pragma unroll
    for (int p = 0; p < 4; p++) {
        int idx = p * 512 + lane * 8;
        int row = idx >> 7;
        int col = idx & 127;
        int R = r0 + row;
        if (R < N_NODES_C)
            *(uint4*)(H + (size_t)R * HID_C + col) = *(const uint4*)&sh[wave][row][col];
    }

    // attention logits from fp32 accumulators
    const float* a_s = asbase + slot * HID_C;
    const float* a_d = adbase + slot * HID_C;
    float* als = alsbase + (size_t)slot * N_NODES_C * HEADS_C;
    float* ald = aldbase + (size_t)slot * N_NODES_C * HEADS_C;
    float ps[4][4], pd[4][4];
#pragma unroll
    for (int h = 0; h < 4; h++) {
        float as0 = a_s[h * 32 + m], as1 = a_s[h * 32 + 16 + m];
        float ad0 = a_d[h * 32 + m], ad1 = a_d[h * 32 + 16 + m];
#pragma unroll
        for (int i = 0; i < 4; i++) {
            ps[h][i] = acc[2 * h][i] * as0 + acc[2 * h + 1][i] * as1;
            pd[h][i] = acc[2 * h][i] * ad0 + acc[2 * h + 1][i] * ad1;
        }
    }
#pragma unroll
    for (int off = 1; off < 16; off <<= 1) {
#pragma unroll
        for (int h = 0; h < 4; h++)
#pragma unroll
            for (int i = 0; i < 4; i++) {
                ps[h][i] += __shfl_xor(ps[h][i], off);
                pd[h][i] += __shfl_xor(pd[h][i], off);
            }
    }
#pragma unroll
    for (int h = 0; h < 4; h++) {
        if (m == h) {
#pragma unroll
            for (int i = 0; i < 4; i++) {
                int R = r0 + quad * 4 + i;
                if (R < N_NODES_C) {
                    als[R * HEADS_C + h] = ps[h][i];
                    ald[R * HEADS_C + h] = pd[h][i];
                }
            }
        }
    }
}

// ========== fused multi-relation aggregate + bias + softsign + LN (layer 2) ==========
__global__ __launch_bounds__(256) void csr_agg_kernel(
    const int* __restrict__ rowptrP, const int* __restrict__ bsums,
    const int* __restrict__ srcids,
    const __half* __restrict__ A, const float* __restrict__ als,
    const float* __restrict__ ald, int rel_start, int rel_cnt,
    const float* __restrict__ bias, int first, int last,
    float* __restrict__ B,
    const float* __restrict__ g, const float* __restrict__ be,
    __half* __restrict__ Cbh) {
    int node = blockIdx.x * 4 + (threadIdx.x >> 6);
    int lane = threadIdx.x & 63;
    int grp = lane >> 4;
    int j16 = lane & 15;
    int head = j16 >> 2;
    int cbase = j16 * 8;

    float acc[8];
    if (first) {
#pragma unroll
        for (int t = 0; t < 8; t++) {
            float s = 0.f;
#pragma unroll
            for (int r = 0; r < N_REL_C; r++) s += bias[r * HID_C + cbase + t];
            acc[t] = s;
        }
    } else {
        float4 b0 = *(const float4*)(B + (size_t)node * HID_C + cbase);
        float4 b1 = *(const float4*)(B + (size_t)node * HID_C + cbase + 4);
        acc[0] = b0.x; acc[1] = b0.y; acc[2] = b0.z; acc[3] = b0.w;
        acc[4] = b1.x; acc[5] = b1.y; acc[6] = b1.z; acc[7] = b1.w;
    }

    for (int j = 0; j < rel_cnt; j++) {
        int r = rel_start + j;
        const int* rp = rowptrP + (size_t)r * (N_NODES_C + 1);
        const int* bs = bsums + r * NBLK_SCAN;
        const int* sp = srcids + (size_t)r * N_EDGES_C;
        const __half* Aj = A + (size_t)j * N_NODES_C * HID_C;
        const float* alj = als + (size_t)j * N_NODES_C * HEADS_C;
        float aldv = ald[(size_t)j * N_NODES_C * HEADS_C + node * HEADS_C + head];
        int s = rp[node] + bs[node >> 8];
        int e = (node == N_NODES_C - 1) ? N_EDGES_C
                                        : rp[node + 1] + bs[(node + 1) >> 8];
        float racc[8];
#pragma unroll
        for (int t = 0; t < 8; t++) racc[t] = 0.f;
        float rden = 0.f;

        union HU { uint4 u; _Float16 h[8]; };
        int i = s + grp;
        int src = (i < e) ? sp[i] : 0;
        HU rw; rw.u = *(const uint4*)(Aj + (size_t)src * HID_C + cbase);
        float lg = alj[src * HEADS_C + head];
        for (; i < e; i += 4) {
            int nsrc = (i + 4 < e) ? sp[i + 4] : 0;
            HU nrw; nrw.u = *(const uint4*)(Aj + (size_t)nsrc * HID_C + cbase);
            float nlg = alj[nsrc * HEADS_C + head];
            float v = lg + aldv;
            v = fmaxf(v, 0.2f * v);          // leaky_relu
            float ex = __expf(v);
            rden += ex;
#pragma unroll
            for (int t = 0; t < 8; t++)
                racc[t] = fmaf((float)rw.h[t], ex, racc[t]);
            src = nsrc; rw = nrw; lg = nlg;
        }
#pragma unroll
        for (int off = 16; off < 64; off <<= 1) {
            rden += __shfl_xor(rden, off);
#pragma unroll
            for (int t = 0; t < 8; t++) racc[t] += __shfl_xor(racc[t], off);
        }
        float inv = 1.f / (rden + 1e-16f);
#pragma unroll
        for (int t = 0; t < 8; t++) acc[t] = fmaf(racc[t], inv, acc[t]);
    }

    if (!last) {
        if (grp == 0) {
            float4 o0 = make_float4(acc[0], acc[1], acc[2], acc[3]);
            float4 o1 = make_float4(acc[4], acc[5], acc[6], acc[7]);
            *(float4*)(B + (size_t)node * HID_C + cbase) = o0;
            *(float4*)(B + (size_t)node * HID_C + cbase + 4) = o1;
        }
    } else {
        float ss[8];
        float sum = 0.f, sq = 0.f;
#pragma unroll
        for (int t = 0; t < 8; t++) {
            float v = acc[t] / (1.f + fabsf(acc[t]));
            ss[t] = v;
            sum += v;
            sq = fmaf(v, v, sq);
        }
#pragma unroll
        for (int off = 1; off < 16; off <<= 1) {
            sum += __shfl_xor(sum, off);
            sq += __shfl_xor(sq, off);
        }
        float mu = sum * (1.f / 128.f);
        float var = sq * (1.f / 128.f) - mu * mu;
        float inv = rsqrtf(var + 1e-5f);
        if (grp == 0) {
            float4 gv0 = *(const float4*)(g + cbase);
            float4 gv1 = *(const float4*)(g + cbase + 4);
            float4 bv0 = *(const float4*)(be + cbase);
            float4 bv1 = *(const float4*)(be + cbase + 4);
            union { uint4 u; __half2 h2[4]; } ow;
            ow.h2[0] = __float22half2_rn(make_float2(
                (ss[0] - mu) * inv * gv0.x + bv0.x, (ss[1] - mu) * inv * gv0.y + bv0.y));
            ow.h2[1] = __float22half2_rn(make_float2(
                (ss[2] - mu) * inv * gv0.z + bv0.z, (ss[3] - mu) * inv * gv0.w + bv0.w));
            ow.h2[2] = __float22half2_rn(make_float2(
                (ss[4] - mu) * inv * gv1.x + bv1.x, (ss[5] - mu) * inv * gv1.y + bv1.y));
            ow.h2[3] = __float22half2_rn(make_float2(
                (ss[6] - mu) * inv * gv1.z + bv1.z, (ss[7] - mu) * inv * gv1.w + bv1.w));
            *(uint4*)(Cbh + (size_t)node * HID_C + cbase) = ow.u;
        }
    }
}

// ================= pooling + projection =================
__device__ __forceinline__ int lower_bound_i(const int* __restrict__ a, int n, int v) {
    int lo = 0, hi = n;
    while (lo < hi) {
        int mid = (lo + hi) >> 1;
        if (a[mid] < v) lo = mid + 1; else hi = mid;
    }
    return lo;
}

__global__ __launch_bounds__(256) void pool_kernel(const __half* __restrict__ H,
                                                   const int* __restrict__ batch,
                                                   const float* __restrict__ q,
                                                   float* __restrict__ pooled) {
    int g = blockIdx.x;
    int t = threadIdx.x;
    int wave = t >> 6, lane = t & 63;
    int start = lower_bound_i(batch, N_NODES_C, g);
    int end = lower_bound_i(batch, N_NODES_C, g + 1);
    float q0 = q[lane * 2], q1 = q[lane * 2 + 1];
    float p0 = 0.f, p1 = 0.f, den = 0.f;
    for (int n = start + wave; n < end; n += 4) {
        float2 hv = __half22float2(*(const __half2*)(H + (size_t)n * HID_C + lane * 2));
        float part = hv.x * q0 + hv.y * q1;
#pragma unroll
        for (int off = 1; off < 64; off <<= 1) part += __shfl_xor(part, off);
        float exs = __expf(part);
        den += exs;
        p0 = fmaf(exs, hv.x, p0);
        p1 = fmaf(exs, hv.y, p1);
    }
    __shared__ float sp[4][HID_C];
    __shared__ float sden[4];
    sp[wave][lane * 2] = p0;
    sp[wave][lane * 2 + 1] = p1;
    if (lane == 0) sden[wave] = den;
    __syncthreads();
    if (wave == 0) {
        float a0 = sp[0][lane * 2] + sp[1][lane * 2] + sp[2][lane * 2] + sp[3][lane * 2];
        float a1 = sp[0][lane * 2 + 1] + sp[1][lane * 2 + 1] + sp[2][lane * 2 + 1] + sp[3][lane * 2 + 1];
        float d = sden[0] + sden[1] + sden[2] + sden[3];
        float w = 1.f / (d + 1e-16f);
        pooled[(size_t)g * HID_C + lane * 2] = a0 * w;
        pooled[(size_t)g * HID_C + lane * 2 + 1] = a1 * w;
    }
}

__global__ __launch_bounds__(128) void proj_kernel(const float* __restrict__ pooled,
                                                   const float* __restrict__ Wp,
                                                   const float* __restrict__ bp,
                                                   float* __restrict__ out) {
    int g = blockIdx.x, c = threadIdx.x;
    __shared__ float pl[HID_C];
    pl[c] = pooled[(size_t)g * HID_C + c];
    __syncthreads();
    float s = bp[c];
    for (int k = 0; k < HID_C; k++) s = fmaf(pl[k], Wp[k * HID_C + c], s);
    out[(size_t)g * HID_C + c] = s;
}

extern "C" void kernel_launch(void* const* d_in, const int* in_sizes, int n_in,
                              void* d_out, int out_size, void* d_ws, size_t ws_size,
                              hipStream_t stream) {
    const float* x   = (const float*)d_in[0];
    const int* ei    = (const int*)d_in[1];
    const int* batch = (const int*)d_in[2];
    const float* W1  = (const float*)d_in[3];
    const float* as1 = (const float*)d_in[4];
    const float* ad1 = (const float*)d_in[5];
    const float* b1  = (const float*)d_in[6];
    const float* W2  = (const float*)d_in[7];
    const float* as2 = (const float*)d_in[8];
    const float* ad2 = (const float*)d_in[9];
    const float* b2  = (const float*)d_in[10];
    const float* g1  = (const float*)d_in[11];
    const float* be1 = (const float*)d_in[12];
    const float* g2  = (const float*)d_in[13];
    const float* be2 = (const float*)d_in[14];
    const float* q   = (const float*)d_in[15];
    const float* Wp  = (const float*)d_in[16];
    const float* bp  = (const float*)d_in[17];
    float* out = (float*)d_out;

    // ---- workspace layout: BYTE-IDENTICAL to the proven round-0 kernel ----
    const size_t NH = (size_t)N_NODES_C * HID_C;
    char* w = (char*)d_ws;
    __half* xh    = (__half*)w;   w += (size_t)N_NODES_C * IN_DIM_C * 2;
    __half* Cbh   = (__half*)w;   w += NH * 2;
    __half* Wt1   = (__half*)w;   w += (size_t)N_REL_C * IN_DIM_C * HID_C * 2;
    __half* Wt2   = (__half*)w;   w += (size_t)N_REL_C * HID_C * HID_C * 2;
    float* pooled = (float*)w;    w += (size_t)N_GRAPHS_C * HID_C * 4;
    int* rowptr   = (int*)w;      w += ((size_t)N_REL_C * (N_NODES_C + 1) * 4 + 15) & ~15ull;
    int* srcids   = (int*)w;      w += (size_t)N_REL_C * N_EDGES_C * 4;
    int* cnt      = (int*)w;      w += (size_t)N_REL_C * N_NODES_C * 4;
    int* bsums    = (int*)w;      w += ((size_t)N_REL_C * NBLK_SCAN * 4 + 15) & ~15ull;

    const size_t fixed_bytes = (size_t)(w - (char*)d_ws);
    const size_t slot_bytes = NH * 2 + 2 * (size_t)N_NODES_C * HEADS_C * 4;
    int nA = 1;
    float* B = nullptr;
    {
        size_t rem = (ws_size > fixed_bytes) ? (ws_size - fixed_bytes) : 0;
        size_t k = rem / slot_bytes;
        if (k >= 6) {
            nA = 6;
        } else {
            size_t rem2 = (rem > NH * 4) ? (rem - NH * 4) : 0;
            size_t k2 = rem2 / slot_bytes;
            nA = (int)(k2 < 1 ? 1 : (k2 > 5 ? 5 : k2));
        }
    }
    float* als = (float*)w;
    float* ald = als + (size_t)nA * N_NODES_C * HEADS_C;
    __half* A  = (__half*)(ald + (size_t)nA * N_NODES_C * HEADS_C);
    if (nA < 6) B = (float*)(A + (size_t)nA * NH);

    // Time-sliced aliases (no net footprint change vs round-0):
    //  - rank: live hist->scatter only (12 MB <= 25.6 MB first A slot)
    int* rank = (int*)A;
    //  - wsd1/wdd1 (12 KB): live hist->logit1; pooled (512 KB) written only at the end
    float* wsd1 = pooled;
    float* wdd1 = pooled + (size_t)N_REL_C * HEADS_C * IN_DIM_C;
    //  - als1/ald1 (19.2 MB): live logit1->agg1; A slab overwritten only by layer-2 gemm
    float* als1 = (float*)A;
    float* ald1 = als1 + (size_t)N_REL_C * N_NODES_C * HEADS_C;

    // ---- CSR build + converts + logit-weight prep (fused first pass) ----
    hipMemsetAsync(cnt, 0, (size_t)N_REL_C * N_NODES_C * sizeof(int), stream);
    const int ehg = (N_REL_C * N_EDGES_C + 255) / 256;
    hist_rank_convert_kernel<<<ehg, 256, 0, stream>>>(ei, cnt, rank, x, xh, W1, W2,
                                                      Wt1, Wt2, as1, ad1, wsd1, wdd1);
    scan1_kernel<<<dim3(NBLK_SCAN, N_REL_C), 256, 0, stream>>>(cnt, rowptr, bsums);
    scan2_kernel<<<N_REL_C, 512, 0, stream>>>(bsums);
    scatter_kernel<<<ehg, 256, 0, stream>>>(ei, rowptr, bsums, rank, srcids);

    // ---- layer 1 (linearity-restructured: logits GEMV + barrier-free fused agg) ----
    logit1_kernel<<<N_NODES_C / 4, 256, 0, stream>>>(xh, wsd1, wdd1, als1, ald1);
    agg1_kernel<<<N_NODES_C / 16, 256, 0, stream>>>(rowptr, bsums, srcids, xh,
                                                    als1, ald1, Wt1, b1, g1, be1, Cbh);

    // ---- layer 2 (unchanged; als1/ald1 dead before gemm writes A) ----
    const int gemm_grid = (N_NODES_C + 63) / 64;
    const int agg_grid = N_NODES_C / 4;
    for (int gs = 0; gs < N_REL_C; gs += nA) {
        int c2 = (N_REL_C - gs) < nA ? (N_REL_C - gs) : nA;
        gemm_mfma_kernel<HID_C><<<dim3(gemm_grid, c2), 256, 0, stream>>>(
            Cbh, Wt2 + (size_t)gs * HID_C * HID_C, A,
            as2 + gs * HID_C, ad2 + gs * HID_C, als, ald);
        csr_agg_kernel<<<agg_grid, 256, 0, stream>>>(
            rowptr, bsums, srcids, A, als, ald, gs, c2,
            b2, (gs == 0) ? 1 : 0, (gs + c2 == N_REL_C) ? 1 : 0,
            B, g2, be2, Cbh);
    }

    // ---- pooling + projection ----
    pool_kernel<<<N_GRAPHS_C, 256, 0, stream>>>(Cbh, batch, q, pooled);
    proj_kernel<<<N_GRAPHS_C, 128, 0, stream>>>(pooled, Wp, bp, out);
}

// Round 4
// 1100.757 us; speedup vs baseline: 1.1234x; 1.1234x over previous
//
#include <hip/hip_runtime.h>
#include <hip/hip_bf16.h>
#include <hip/hip_fp16.h>

#define N_NODES_C 100000
#define N_EDGES_C 500000
#define N_REL_C 6
#define IN_DIM_C 64
#define HID_C 128
#define HEADS_C 4
#define CPH_C 32
#define N_GRAPHS_C 1024
#define NBLK_SCAN 391   // ceil(100000/256)
#define SH_PAD 8        // LDS transpose row pad (halves): 2-way banks, 16B aligned

typedef _Float16 f16x8 __attribute__((ext_vector_type(8)));
typedef float f32x4 __attribute__((ext_vector_type(4)));

// ========== CSR hist+rank, fused with fp32->fp16 converts ==========
__global__ __launch_bounds__(256) void hist_rank_convert_kernel(
    const int* __restrict__ ei, int* __restrict__ cnt, int* __restrict__ rank,
    const float* __restrict__ x, __half* __restrict__ xh,
    const float* __restrict__ W1, const float* __restrict__ W2,
    __half* __restrict__ Wt1, __half* __restrict__ Wt2) {
    int i = blockIdx.x * 256 + threadIdx.x;
    // convert x (1.6M float4 groups)
    if (i < N_NODES_C * IN_DIM_C / 4) {
        float4 v = ((const float4*)x)[i];
        union { __half h[4]; uint2 u; } u;
        u.h[0] = __float2half(v.x); u.h[1] = __float2half(v.y);
        u.h[2] = __float2half(v.z); u.h[3] = __float2half(v.w);
        ((uint2*)xh)[i] = u.u;
    }
    // convert + transpose W1, W2
    if (i < N_REL_C * IN_DIM_C * HID_C) {
        int r = i / (IN_DIM_C * HID_C);
        int rem = i - r * (IN_DIM_C * HID_C);
        int k = rem / HID_C, n = rem - k * HID_C;
        Wt1[(size_t)r * HID_C * IN_DIM_C + n * IN_DIM_C + k] = __float2half(W1[i]);
    }
    if (i < N_REL_C * HID_C * HID_C) {
        int r = i / (HID_C * HID_C);
        int rem = i - r * (HID_C * HID_C);
        int k = rem / HID_C, n = rem - k * HID_C;
        Wt2[(size_t)r * HID_C * HID_C + n * HID_C + k] = __float2half(W2[i]);
    }
    // histogram + per-edge rank
    if (i < N_REL_C * N_EDGES_C) {
        int r = i / N_EDGES_C;
        int e = i - r * N_EDGES_C;
        int dst = ei[(size_t)r * 2 * N_EDGES_C + N_EDGES_C + e];
        rank[i] = atomicAdd(&cnt[r * N_NODES_C + dst], 1);
    }
}

// per-256-block exclusive scan; bsums[r][b] = block total
__global__ __launch_bounds__(256) void scan1_kernel(const int* __restrict__ cnt,
                                                    int* __restrict__ rowptr,
                                                    int* __restrict__ blocksums) {
    int r = blockIdx.y, b = blockIdx.x, t = threadIdx.x;
    int idx = b * 256 + t;
    int v = (idx < N_NODES_C) ? cnt[r * N_NODES_C + idx] : 0;
    int orig = v;
    int lane = t & 63, w = t >> 6;
#pragma unroll
    for (int off = 1; off < 64; off <<= 1) {
        int n = __shfl_up(v, off);
        if (lane >= off) v += n;
    }
    __shared__ int wt[4];
    if (lane == 63) wt[w] = v;
    __syncthreads();
    int add = 0;
    for (int i = 0; i < w; i++) add += wt[i];
    v += add;
    if (idx < N_NODES_C) rowptr[(size_t)r * (N_NODES_C + 1) + idx] = v - orig;
    if (t == 255) blocksums[r * NBLK_SCAN + b] = v;
}

// scan block sums -> exclusive prefixes (final rowptr = rowptrP + bsums[b])
__global__ __launch_bounds__(512) void scan2_kernel(int* __restrict__ blocksums) {
    int r = blockIdx.x, t = threadIdx.x;
    int v = (t < NBLK_SCAN) ? blocksums[r * NBLK_SCAN + t] : 0;
    int orig = v;
    int lane = t & 63, w = t >> 6;
#pragma unroll
    for (int off = 1; off < 64; off <<= 1) {
        int n = __shfl_up(v, off);
        if (lane >= off) v += n;
    }
    __shared__ int wt[8];
    if (lane == 63) wt[w] = v;
    __syncthreads();
    int add = 0;
    for (int i = 0; i < w; i++) add += wt[i];
    v += add;
    if (t < NBLK_SCAN) blocksums[r * NBLK_SCAN + t] = v - orig;
}

// atomic-free scatter; final rowptr computed inline
__global__ __launch_bounds__(256) void scatter_kernel(const int* __restrict__ ei,
                                                      const int* __restrict__ rowptrP,
                                                      const int* __restrict__ bsums,
                                                      const int* __restrict__ rank,
                                                      int* __restrict__ srcids) {
    int i = blockIdx.x * 256 + threadIdx.x;
    if (i >= N_REL_C * N_EDGES_C) return;
    int r = i / N_EDGES_C;
    int e = i - r * N_EDGES_C;
    int src = ei[(size_t)r * 2 * N_EDGES_C + e];
    int dst = ei[(size_t)r * 2 * N_EDGES_C + N_EDGES_C + e];
    int base = rowptrP[(size_t)r * (N_NODES_C + 1) + dst] + bsums[r * NBLK_SCAN + (dst >> 8)];
    srcids[(size_t)r * N_EDGES_C + base + rank[i]] = src;
}

// ================= fp16 MFMA GEMM + attn-logit epilogue =================
// grid.y = relation slot; LDS transpose buffer padded (bank-conflict-free).
template <int K>
__global__ __launch_bounds__(256) void gemm_mfma_kernel(
    const __half* __restrict__ Xh, const __half* __restrict__ Wtbase,
    __half* __restrict__ Hbase,
    const float* __restrict__ asbase, const float* __restrict__ adbase,
    float* __restrict__ alsbase, float* __restrict__ aldbase) {
    __shared__ _Float16 sh[4][16][HID_C + SH_PAD];
    const int slot = blockIdx.y;
    const __half* Wt = Wtbase + (size_t)slot * HID_C * K;
    __half* H = Hbase + (size_t)slot * N_NODES_C * HID_C;
    const int wave = threadIdx.x >> 6, lane = threadIdx.x & 63;
    const int r0 = blockIdx.x * 64 + wave * 16;
    const int m = lane & 15, quad = lane >> 4;
    int arow = r0 + m;
    if (arow > N_NODES_C - 1) arow = N_NODES_C - 1;
    const __half* ap = Xh + (size_t)arow * K + quad * 8;
    const __half* bp = Wt + (size_t)m * K + quad * 8;

    f32x4 acc[8];
#pragma unroll
    for (int t = 0; t < 8; t++) acc[t] = (f32x4){0.f, 0.f, 0.f, 0.f};

#pragma unroll
    for (int kc = 0; kc < K; kc += 32) {
        f16x8 a = *(const f16x8*)(ap + kc);
#pragma unroll
        for (int t = 0; t < 8; t++) {
            f16x8 b = *(const f16x8*)(bp + (size_t)t * 16 * K + kc);
            acc[t] = __builtin_amdgcn_mfma_f32_16x16x32_f16(a, b, acc[t], 0, 0, 0);
        }
    }

    // transpose C-layout -> row-major via LDS (same-wave: no barrier needed)
#pragma unroll
    for (int t = 0; t < 8; t++)
#pragma unroll
        for (int i = 0; i < 4; i++)
            sh[wave][quad * 4 + i][t * 16 + m] = (_Float16)acc[t][i];
#pragma unroll
    for (int p = 0; p < 4; p++) {
        int idx = p * 512 + lane * 8;
        int row = idx >> 7;
        int col = idx & 127;
        int R = r0 + row;
        if (R < N_NODES_C)
            *(uint4*)(H + (size_t)R * HID_C + col) = *(const uint4*)&sh[wave][row][col];
    }

    // attention logits from fp32 accumulators
    const float* a_s = asbase + slot * HID_C;
    const float* a_d = adbase + slot * HID_C;
    float* als = alsbase + (size_t)slot * N_NODES_C * HEADS_C;
    float* ald = aldbase + (size_t)slot * N_NODES_C * HEADS_C;
    float ps[4][4], pd[4][4];
#pragma unroll
    for (int h = 0; h < 4; h++) {
        float as0 = a_s[h * 32 + m], as1 = a_s[h * 32 + 16 + m];
        float ad0 = a_d[h * 32 + m], ad1 = a_d[h * 32 + 16 + m];
#pragma unroll
        for (int i = 0; i < 4; i++) {
            ps[h][i] = acc[2 * h][i] * as0 + acc[2 * h + 1][i] * as1;
            pd[h][i] = acc[2 * h][i] * ad0 + acc[2 * h + 1][i] * ad1;
        }
    }
#pragma unroll
    for (int off = 1; off < 16; off <<= 1) {
#pragma unroll
        for (int h = 0; h < 4; h++)
#pragma unroll
            for (int i = 0; i < 4; i++) {
                ps[h][i] += __shfl_xor(ps[h][i], off);
                pd[h][i] += __shfl_xor(pd[h][i], off);
            }
    }
#pragma unroll
    for (int h = 0; h < 4; h++) {
        if (m == h) {
#pragma unroll
            for (int i = 0; i < 4; i++) {
                int R = r0 + quad * 4 + i;
                if (R < N_NODES_C) {
                    als[R * HEADS_C + h] = ps[h][i];
                    ald[R * HEADS_C + h] = pd[h][i];
                }
            }
        }
    }
}

// ========== fused multi-relation aggregate + bias + softsign + LN ==========
// Deferred reduction: per relation only rden is cross-group reduced (2 shfl);
// alpha-normalized partials accumulate per-lane and the 8-value cross-group
// reduce happens ONCE after the relation loop (inv distributes over group sums).
// 2-deep edge prefetch for latency hiding. node0 = node-range split for profiling.
__global__ __launch_bounds__(256) void csr_agg_kernel(
    const int* __restrict__ rowptrP, const int* __restrict__ bsums,
    const int* __restrict__ srcids,
    const __half* __restrict__ A, const float* __restrict__ als,
    const float* __restrict__ ald, int rel_start, int rel_cnt,
    const float* __restrict__ bias, int first, int last,
    float* __restrict__ B,
    const float* __restrict__ g, const float* __restrict__ be,
    __half* __restrict__ Cbh, int node0) {
    int node = node0 + blockIdx.x * 4 + (threadIdx.x >> 6);
    int lane = threadIdx.x & 63;
    int grp = lane >> 4;
    int j16 = lane & 15;
    int head = j16 >> 2;
    int cbase = j16 * 8;

    float accp[8];
#pragma unroll
    for (int t = 0; t < 8; t++) accp[t] = 0.f;

    for (int j = 0; j < rel_cnt; j++) {
        int r = rel_start + j;
        const int* rp = rowptrP + (size_t)r * (N_NODES_C + 1);
        const int* bs = bsums + r * NBLK_SCAN;
        const int* sp = srcids + (size_t)r * N_EDGES_C;
        const __half* Aj = A + (size_t)j * N_NODES_C * HID_C;
        const float* alj = als + (size_t)j * N_NODES_C * HEADS_C;
        float aldv = ald[(size_t)j * N_NODES_C * HEADS_C + node * HEADS_C + head];
        int s = rp[node] + bs[node >> 8];
        int e = (node == N_NODES_C - 1) ? N_EDGES_C
                                        : rp[node + 1] + bs[(node + 1) >> 8];
        float racc[8];
#pragma unroll
        for (int t = 0; t < 8; t++) racc[t] = 0.f;
        float rden = 0.f;

        union HU { uint4 u; _Float16 h[8]; };
        int i = s + grp;
        // 2-deep prologue (OOB clamps to row 0: cached, harmless)
        int s0 = (i < e) ? sp[i] : 0;
        HU rw0; rw0.u = *(const uint4*)(Aj + (size_t)s0 * HID_C + cbase);
        float lg0 = alj[s0 * HEADS_C + head];
        int s1 = (i + 4 < e) ? sp[i + 4] : 0;
        HU rw1; rw1.u = *(const uint4*)(Aj + (size_t)s1 * HID_C + cbase);
        float lg1 = alj[s1 * HEADS_C + head];
        for (; i < e; i += 4) {
            int ns = (i + 8 < e) ? sp[i + 8] : 0;
            HU nrw; nrw.u = *(const uint4*)(Aj + (size_t)ns * HID_C + cbase);
            float nlg = alj[ns * HEADS_C + head];
            float v = lg0 + aldv;
            v = fmaxf(v, 0.2f * v);          // leaky_relu
            float ex = __expf(v);
            rden += ex;
#pragma unroll
            for (int t = 0; t < 8; t++)
                racc[t] = fmaf((float)rw0.h[t], ex, racc[t]);
            rw0 = rw1; lg0 = lg1;
            rw1 = nrw; lg1 = nlg;
        }
        // only the denominator needs per-relation reduction
        rden += __shfl_xor(rden, 16);
        rden += __shfl_xor(rden, 32);
        float inv = __builtin_amdgcn_rcpf(rden + 1e-16f);
#pragma unroll
        for (int t = 0; t < 8; t++) accp[t] = fmaf(racc[t], inv, accp[t]);
    }

    // single cross-group reduce for all relations' contributions
#pragma unroll
    for (int off = 16; off < 64; off <<= 1) {
#pragma unroll
        for (int t = 0; t < 8; t++) accp[t] += __shfl_xor(accp[t], off);
    }

    float acc[8];
    if (first) {
#pragma unroll
        for (int t = 0; t < 8; t++) {
            float sbias = 0.f;
#pragma unroll
            for (int r = 0; r < N_REL_C; r++) sbias += bias[r * HID_C + cbase + t];
            acc[t] = sbias + accp[t];
        }
    } else {
        float4 b0 = *(const float4*)(B + (size_t)node * HID_C + cbase);
        float4 b1 = *(const float4*)(B + (size_t)node * HID_C + cbase + 4);
        acc[0] = b0.x + accp[0]; acc[1] = b0.y + accp[1];
        acc[2] = b0.z + accp[2]; acc[3] = b0.w + accp[3];
        acc[4] = b1.x + accp[4]; acc[5] = b1.y + accp[5];
        acc[6] = b1.z + accp[6]; acc[7] = b1.w + accp[7];
    }

    if (!last) {
        if (grp == 0) {
            float4 o0 = make_float4(acc[0], acc[1], acc[2], acc[3]);
            float4 o1 = make_float4(acc[4], acc[5], acc[6], acc[7]);
            *(float4*)(B + (size_t)node * HID_C + cbase) = o0;
            *(float4*)(B + (size_t)node * HID_C + cbase + 4) = o1;
        }
    } else {
        float ss[8];
        float sum = 0.f, sq = 0.f;
#pragma unroll
        for (int t = 0; t < 8; t++) {
            float v = acc[t] / (1.f + fabsf(acc[t]));
            ss[t] = v;
            sum += v;
            sq = fmaf(v, v, sq);
        }
#pragma unroll
        for (int off = 1; off < 16; off <<= 1) {
            sum += __shfl_xor(sum, off);
            sq += __shfl_xor(sq, off);
        }
        float mu = sum * (1.f / 128.f);
        float var = sq * (1.f / 128.f) - mu * mu;
        float inv = rsqrtf(var + 1e-5f);
        if (grp == 0) {
            float4 gv0 = *(const float4*)(g + cbase);
            float4 gv1 = *(const float4*)(g + cbase + 4);
            float4 bv0 = *(const float4*)(be + cbase);
            float4 bv1 = *(const float4*)(be + cbase + 4);
            union { uint4 u; __half2 h2[4]; } ow;
            ow.h2[0] = __float22half2_rn(make_float2(
                (ss[0] - mu) * inv * gv0.x + bv0.x, (ss[1] - mu) * inv * gv0.y + bv0.y));
            ow.h2[1] = __float22half2_rn(make_float2(
                (ss[2] - mu) * inv * gv0.z + bv0.z, (ss[3] - mu) * inv * gv0.w + bv0.w));
            ow.h2[2] = __float22half2_rn(make_float2(
                (ss[4] - mu) * inv * gv1.x + bv1.x, (ss[5] - mu) * inv * gv1.y + bv1.y));
            ow.h2[3] = __float22half2_rn(make_float2(
                (ss[6] - mu) * inv * gv1.z + bv1.z, (ss[7] - mu) * inv * gv1.w + bv1.w));
            *(uint4*)(Cbh + (size_t)node * HID_C + cbase) = ow.u;
        }
    }
}

// ================= pooling + projection =================
__device__ __forceinline__ int lower_bound_i(const int* __restrict__ a, int n, int v) {
    int lo = 0, hi = n;
    while (lo < hi) {
        int mid = (lo + hi) >> 1;
        if (a[mid] < v) lo = mid + 1; else hi = mid;
    }
    return lo;
}

__global__ __launch_bounds__(256) void pool_kernel(const __half* __restrict__ H,
                                                   const int* __restrict__ batch,
                                                   const float* __restrict__ q,
                                                   float* __restrict__ pooled) {
    int g = blockIdx.x;
    int t = threadIdx.x;
    int wave = t >> 6, lane = t & 63;
    int start = lower_bound_i(batch, N_NODES_C, g);
    int end = lower_bound_i(batch, N_NODES_C, g + 1);
    float q0 = q[lane * 2], q1 = q[lane * 2 + 1];
    float p0 = 0.f, p1 = 0.f, den = 0.f;
    for (int n = start + wave; n < end; n += 4) {
        float2 hv = __half22float2(*(const __half2*)(H + (size_t)n * HID_C + lane * 2));
        float part = hv.x * q0 + hv.y * q1;
#pragma unroll
        for (int off = 1; off < 64; off <<= 1) part += __shfl_xor(part, off);
        float exs = __expf(part);
        den += exs;
        p0 = fmaf(exs, hv.x, p0);
        p1 = fmaf(exs, hv.y, p1);
    }
    __shared__ float sp[4][HID_C];
    __shared__ float sden[4];
    sp[wave][lane * 2] = p0;
    sp[wave][lane * 2 + 1] = p1;
    if (lane == 0) sden[wave] = den;
    __syncthreads();
    if (wave == 0) {
        float a0 = sp[0][lane * 2] + sp[1][lane * 2] + sp[2][lane * 2] + sp[3][lane * 2];
        float a1 = sp[0][lane * 2 + 1] + sp[1][lane * 2 + 1] + sp[2][lane * 2 + 1] + sp[3][lane * 2 + 1];
        float d = sden[0] + sden[1] + sden[2] + sden[3];
        float w = 1.f / (d + 1e-16f);
        pooled[(size_t)g * HID_C + lane * 2] = a0 * w;
        pooled[(size_t)g * HID_C + lane * 2 + 1] = a1 * w;
    }
}

__global__ __launch_bounds__(128) void proj_kernel(const float* __restrict__ pooled,
                                                   const float* __restrict__ Wp,
                                                   const float* __restrict__ bp,
                                                   float* __restrict__ out) {
    int g = blockIdx.x, c = threadIdx.x;
    __shared__ float pl[HID_C];
    pl[c] = pooled[(size_t)g * HID_C + c];
    __syncthreads();
    float s = bp[c];
    for (int k = 0; k < HID_C; k++) s = fmaf(pl[k], Wp[k * HID_C + c], s);
    out[(size_t)g * HID_C + c] = s;
}

extern "C" void kernel_launch(void* const* d_in, const int* in_sizes, int n_in,
                              void* d_out, int out_size, void* d_ws, size_t ws_size,
                              hipStream_t stream) {
    const float* x   = (const float*)d_in[0];
    const int* ei    = (const int*)d_in[1];
    const int* batch = (const int*)d_in[2];
    const float* W1  = (const float*)d_in[3];
    const float* as1 = (const float*)d_in[4];
    const float* ad1 = (const float*)d_in[5];
    const float* b1  = (const float*)d_in[6];
    const float* W2  = (const float*)d_in[7];
    const float* as2 = (const float*)d_in[8];
    const float* ad2 = (const float*)d_in[9];
    const float* b2  = (const float*)d_in[10];
    const float* g1  = (const float*)d_in[11];
    const float* be1 = (const float*)d_in[12];
    const float* g2  = (const float*)d_in[13];
    const float* be2 = (const float*)d_in[14];
    const float* q   = (const float*)d_in[15];
    const float* Wp  = (const float*)d_in[16];
    const float* bp  = (const float*)d_in[17];
    float* out = (float*)d_out;

    // ---- workspace layout: identical to the proven round-0 kernel ----
    const size_t NH = (size_t)N_NODES_C * HID_C;
    char* w = (char*)d_ws;
    __half* xh    = (__half*)w;   w += (size_t)N_NODES_C * IN_DIM_C * 2;
    __half* Cbh   = (__half*)w;   w += NH * 2;
    __half* Wt1   = (__half*)w;   w += (size_t)N_REL_C * IN_DIM_C * HID_C * 2;
    __half* Wt2   = (__half*)w;   w += (size_t)N_REL_C * HID_C * HID_C * 2;
    float* pooled = (float*)w;    w += (size_t)N_GRAPHS_C * HID_C * 4;
    int* rowptr   = (int*)w;      w += ((size_t)N_REL_C * (N_NODES_C + 1) * 4 + 15) & ~15ull;
    int* srcids   = (int*)w;      w += (size_t)N_REL_C * N_EDGES_C * 4;
    int* cnt      = (int*)w;      w += (size_t)N_REL_C * N_NODES_C * 4;
    int* bsums    = (int*)w;      w += ((size_t)N_REL_C * NBLK_SCAN * 4 + 15) & ~15ull;

    const size_t fixed_bytes = (size_t)(w - (char*)d_ws);
    const size_t slot_bytes = NH * 2 + 2 * (size_t)N_NODES_C * HEADS_C * 4;
    int nA = 1;
    float* B = nullptr;
    {
        size_t rem = (ws_size > fixed_bytes) ? (ws_size - fixed_bytes) : 0;
        size_t k = rem / slot_bytes;
        if (k >= 6) {
            nA = 6;
        } else {
            size_t rem2 = (rem > NH * 4) ? (rem - NH * 4) : 0;
            size_t k2 = rem2 / slot_bytes;
            nA = (int)(k2 < 1 ? 1 : (k2 > 5 ? 5 : k2));
        }
    }
    float* als = (float*)w;
    float* ald = als + (size_t)nA * N_NODES_C * HEADS_C;
    __half* A  = (__half*)(ald + (size_t)nA * N_NODES_C * HEADS_C);
    if (nA < 6) B = (float*)(A + (size_t)nA * NH);
    // rank[] only live during CSR build, before A is written: alias into A slab
    int* rank = (int*)A;   // 12 MB <= 25.6 MB (first slot)

    // ---- CSR build + converts (fused first pass) ----
    hipMemsetAsync(cnt, 0, (size_t)N_REL_C * N_NODES_C * sizeof(int), stream);
    const int ehg = (N_REL_C * N_EDGES_C + 255) / 256;
    hist_rank_convert_kernel<<<ehg, 256, 0, stream>>>(ei, cnt, rank, x, xh, W1, W2, Wt1, Wt2);
    scan1_kernel<<<dim3(NBLK_SCAN, N_REL_C), 256, 0, stream>>>(cnt, rowptr, bsums);
    scan2_kernel<<<N_REL_C, 512, 0, stream>>>(bsums);
    scatter_kernel<<<ehg, 256, 0, stream>>>(ei, rowptr, bsums, rank, srcids);

    const int gemm_grid = (N_NODES_C + 63) / 64;
    const int agg_grid_half = N_NODES_C / 8;   // node-range split: 2 dispatches

    // ---- layer 1 ----
    for (int gs = 0; gs < N_REL_C; gs += nA) {
        int c2 = (N_REL_C - gs) < nA ? (N_REL_C - gs) : nA;
        gemm_mfma_kernel<IN_DIM_C><<<dim3(gemm_grid, c2), 256, 0, stream>>>(
            xh, Wt1 + (size_t)gs * IN_DIM_C * HID_C, A,
            as1 + gs * HID_C, ad1 + gs * HID_C, als, ald);
        csr_agg_kernel<<<agg_grid_half, 256, 0, stream>>>(
            rowptr, bsums, srcids, A, als, ald, gs, c2,
            b1, (gs == 0) ? 1 : 0, (gs + c2 == N_REL_C) ? 1 : 0,
            B, g1, be1, Cbh, 0);
        csr_agg_kernel<<<agg_grid_half, 256, 0, stream>>>(
            rowptr, bsums, srcids, A, als, ald, gs, c2,
            b1, (gs == 0) ? 1 : 0, (gs + c2 == N_REL_C) ? 1 : 0,
            B, g1, be1, Cbh, N_NODES_C / 2);
    }
    // ---- layer 2 ----
    for (int gs = 0; gs < N_REL_C; gs += nA) {
        int c2 = (N_REL_C - gs) < nA ? (N_REL_C - gs) : nA;
        gemm_mfma_kernel<HID_C><<<dim3(gemm_grid, c2), 256, 0, stream>>>(
            Cbh, Wt2 + (size_t)gs * HID_C * HID_C, A,
            as2 + gs * HID_C, ad2 + gs * HID_C, als, ald);
        csr_agg_kernel<<<agg_grid_half, 256, 0, stream>>>(
            rowptr, bsums, srcids, A, als, ald, gs, c2,
            b2, (gs == 0) ? 1 : 0, (gs + c2 == N_REL_C) ? 1 : 0,
            B, g2, be2, Cbh, 0);
        csr_agg_kernel<<<agg_grid_half, 256, 0, stream>>>(
            rowptr, bsums, srcids, A, als, ald, gs, c2,
            b2, (gs == 0) ? 1 : 0, (gs + c2 == N_REL_C) ? 1 : 0,
            B, g2, be2, Cbh, N_NODES_C / 2);
    }

    // ---- pooling + projection ----
    pool_kernel<<<N_GRAPHS_C, 256, 0, stream>>>(Cbh, batch, q, pooled);
    proj_kernel<<<N_GRAPHS_C, 128, 0, stream>>>(pooled, Wp, bp, out);
}

// Round 5
// 1080.544 us; speedup vs baseline: 1.1445x; 1.0187x over previous
//
#include <hip/hip_runtime.h>
#include <hip/hip_bf16.h>
#include <hip/hip_fp16.h>

#define N_NODES_C 100000
#define N_EDGES_C 500000
#define N_REL_C 6
#define IN_DIM_C 64
#define HID_C 128
#define HEADS_C 4
#define CPH_C 32
#define N_GRAPHS_C 1024
#define NBLK_SCAN 391   // ceil(100000/256)
#define SH_PAD 8        // LDS transpose row pad (halves): 2-way banks, 16B aligned

typedef _Float16 f16x8 __attribute__((ext_vector_type(8)));
typedef float f32x4 __attribute__((ext_vector_type(4)));

// ========== CSR hist+rank, fused with fp32->fp16 converts ==========
__global__ __launch_bounds__(256) void hist_rank_convert_kernel(
    const int* __restrict__ ei, int* __restrict__ cnt, int* __restrict__ rank,
    const float* __restrict__ x, __half* __restrict__ xh,
    const float* __restrict__ W1, const float* __restrict__ W2,
    __half* __restrict__ Wt1, __half* __restrict__ Wt2) {
    int i = blockIdx.x * 256 + threadIdx.x;
    // convert x (1.6M float4 groups)
    if (i < N_NODES_C * IN_DIM_C / 4) {
        float4 v = ((const float4*)x)[i];
        union { __half h[4]; uint2 u; } u;
        u.h[0] = __float2half(v.x); u.h[1] = __float2half(v.y);
        u.h[2] = __float2half(v.z); u.h[3] = __float2half(v.w);
        ((uint2*)xh)[i] = u.u;
    }
    // convert + transpose W1, W2
    if (i < N_REL_C * IN_DIM_C * HID_C) {
        int r = i / (IN_DIM_C * HID_C);
        int rem = i - r * (IN_DIM_C * HID_C);
        int k = rem / HID_C, n = rem - k * HID_C;
        Wt1[(size_t)r * HID_C * IN_DIM_C + n * IN_DIM_C + k] = __float2half(W1[i]);
    }
    if (i < N_REL_C * HID_C * HID_C) {
        int r = i / (HID_C * HID_C);
        int rem = i - r * (HID_C * HID_C);
        int k = rem / HID_C, n = rem - k * HID_C;
        Wt2[(size_t)r * HID_C * HID_C + n * HID_C + k] = __float2half(W2[i]);
    }
    // histogram + per-edge rank
    if (i < N_REL_C * N_EDGES_C) {
        int r = i / N_EDGES_C;
        int e = i - r * N_EDGES_C;
        int dst = ei[(size_t)r * 2 * N_EDGES_C + N_EDGES_C + e];
        rank[i] = atomicAdd(&cnt[r * N_NODES_C + dst], 1);
    }
}

// per-256-block exclusive scan; bsums[r][b] = block total
__global__ __launch_bounds__(256) void scan1_kernel(const int* __restrict__ cnt,
                                                    int* __restrict__ rowptr,
                                                    int* __restrict__ blocksums) {
    int r = blockIdx.y, b = blockIdx.x, t = threadIdx.x;
    int idx = b * 256 + t;
    int v = (idx < N_NODES_C) ? cnt[r * N_NODES_C + idx] : 0;
    int orig = v;
    int lane = t & 63, w = t >> 6;
#pragma unroll
    for (int off = 1; off < 64; off <<= 1) {
        int n = __shfl_up(v, off);
        if (lane >= off) v += n;
    }
    __shared__ int wt[4];
    if (lane == 63) wt[w] = v;
    __syncthreads();
    int add = 0;
    for (int i = 0; i < w; i++) add += wt[i];
    v += add;
    if (idx < N_NODES_C) rowptr[(size_t)r * (N_NODES_C + 1) + idx] = v - orig;
    if (t == 255) blocksums[r * NBLK_SCAN + b] = v;
}

// scan block sums -> exclusive prefixes (final rowptr = rowptrP + bsums[b])
__global__ __launch_bounds__(512) void scan2_kernel(int* __restrict__ blocksums) {
    int r = blockIdx.x, t = threadIdx.x;
    int v = (t < NBLK_SCAN) ? blocksums[r * NBLK_SCAN + t] : 0;
    int orig = v;
    int lane = t & 63, w = t >> 6;
#pragma unroll
    for (int off = 1; off < 64; off <<= 1) {
        int n = __shfl_up(v, off);
        if (lane >= off) v += n;
    }
    __shared__ int wt[8];
    if (lane == 63) wt[w] = v;
    __syncthreads();
    int add = 0;
    for (int i = 0; i < w; i++) add += wt[i];
    v += add;
    if (t < NBLK_SCAN) blocksums[r * NBLK_SCAN + t] = v - orig;
}

// atomic-free scatter; final rowptr computed inline
__global__ __launch_bounds__(256) void scatter_kernel(const int* __restrict__ ei,
                                                      const int* __restrict__ rowptrP,
                                                      const int* __restrict__ bsums,
                                                      const int* __restrict__ rank,
                                                      int* __restrict__ srcids) {
    int i = blockIdx.x * 256 + threadIdx.x;
    if (i >= N_REL_C * N_EDGES_C) return;
    int r = i / N_EDGES_C;
    int e = i - r * N_EDGES_C;
    int src = ei[(size_t)r * 2 * N_EDGES_C + e];
    int dst = ei[(size_t)r * 2 * N_EDGES_C + N_EDGES_C + e];
    int base = rowptrP[(size_t)r * (N_NODES_C + 1) + dst] + bsums[r * NBLK_SCAN + (dst >> 8)];
    srcids[(size_t)r * N_EDGES_C + base + rank[i]] = src;
}

// ================= fp16 MFMA GEMM + attn-logit epilogue =================
// Relation loop INSIDE: A-fragments loaded once into registers, reused across
// all 6 relation slots (6x fewer blocks, amortized prologue, A fetched once).
// LDS transpose buffer is per-wave and reused per relation (same-wave ordering).
template <int K>
__global__ __launch_bounds__(256) void gemm_mfma_kernel(
    const __half* __restrict__ Xh, const __half* __restrict__ Wtbase,
    __half* __restrict__ Hbase,
    const float* __restrict__ asbase, const float* __restrict__ adbase,
    float* __restrict__ alsbase, float* __restrict__ aldbase, int nslots) {
    __shared__ _Float16 sh[4][16][HID_C + SH_PAD];
    const int wave = threadIdx.x >> 6, lane = threadIdx.x & 63;
    const int r0 = blockIdx.x * 64 + wave * 16;
    const int m = lane & 15, quad = lane >> 4;
    int arow = r0 + m;
    if (arow > N_NODES_C - 1) arow = N_NODES_C - 1;
    const __half* ap = Xh + (size_t)arow * K + quad * 8;

    // preload A fragments once (K/32 x f16x8 = 8 or 16 VGPRs)
    f16x8 afrag[K / 32];
#pragma unroll
    for (int kc = 0; kc < K / 32; kc++) afrag[kc] = *(const f16x8*)(ap + kc * 32);

    for (int slot = 0; slot < nslots; slot++) {
        const __half* Wt = Wtbase + (size_t)slot * HID_C * K;
        __half* H = Hbase + (size_t)slot * N_NODES_C * HID_C;
        const __half* bp = Wt + (size_t)m * K + quad * 8;

        f32x4 acc[8];
#pragma unroll
        for (int t = 0; t < 8; t++) acc[t] = (f32x4){0.f, 0.f, 0.f, 0.f};

#pragma unroll
        for (int kc = 0; kc < K / 32; kc++) {
#pragma unroll
            for (int t = 0; t < 8; t++) {
                f16x8 b = *(const f16x8*)(bp + (size_t)t * 16 * K + kc * 32);
                acc[t] = __builtin_amdgcn_mfma_f32_16x16x32_f16(afrag[kc], b, acc[t], 0, 0, 0);
            }
        }

        // transpose C-layout -> row-major via LDS (same-wave: no barrier needed)
#pragma unroll
        for (int t = 0; t < 8; t++)
#pragma unroll
            for (int i = 0; i < 4; i++)
                sh[wave][quad * 4 + i][t * 16 + m] = (_Float16)acc[t][i];
#pragma unroll
        for (int p = 0; p < 4; p++) {
            int idx = p * 512 + lane * 8;
            int row = idx >> 7;
            int col = idx & 127;
            int R = r0 + row;
            if (R < N_NODES_C)
                *(uint4*)(H + (size_t)R * HID_C + col) = *(const uint4*)&sh[wave][row][col];
        }

        // attention logits from fp32 accumulators
        const float* a_s = asbase + slot * HID_C;
        const float* a_d = adbase + slot * HID_C;
        float* als = alsbase + (size_t)slot * N_NODES_C * HEADS_C;
        float* ald = aldbase + (size_t)slot * N_NODES_C * HEADS_C;
        float ps[4][4], pd[4][4];
#pragma unroll
        for (int h = 0; h < 4; h++) {
            float as0 = a_s[h * 32 + m], as1 = a_s[h * 32 + 16 + m];
            float ad0 = a_d[h * 32 + m], ad1 = a_d[h * 32 + 16 + m];
#pragma unroll
            for (int i = 0; i < 4; i++) {
                ps[h][i] = acc[2 * h][i] * as0 + acc[2 * h + 1][i] * as1;
                pd[h][i] = acc[2 * h][i] * ad0 + acc[2 * h + 1][i] * ad1;
            }
        }
#pragma unroll
        for (int off = 1; off < 16; off <<= 1) {
#pragma unroll
            for (int h = 0; h < 4; h++)
#pragma unroll
                for (int i = 0; i < 4; i++) {
                    ps[h][i] += __shfl_xor(ps[h][i], off);
                    pd[h][i] += __shfl_xor(pd[h][i], off);
                }
        }
#pragma unroll
        for (int h = 0; h < 4; h++) {
            if (m == h) {
#pragma unroll
                for (int i = 0; i < 4; i++) {
                    int R = r0 + quad * 4 + i;
                    if (R < N_NODES_C) {
                        als[R * HEADS_C + h] = ps[h][i];
                        ald[R * HEADS_C + h] = pd[h][i];
                    }
                }
            }
        }
    }
}

// ========== fused multi-relation aggregate + bias + softsign + LN ==========
// (exact round-0 body: 1-deep prefetch, per-relation full reduce)
__global__ __launch_bounds__(256) void csr_agg_kernel(
    const int* __restrict__ rowptrP, const int* __restrict__ bsums,
    const int* __restrict__ srcids,
    const __half* __restrict__ A, const float* __restrict__ als,
    const float* __restrict__ ald, int rel_start, int rel_cnt,
    const float* __restrict__ bias, int first, int last,
    float* __restrict__ B,
    const float* __restrict__ g, const float* __restrict__ be,
    __half* __restrict__ Cbh) {
    int node = blockIdx.x * 4 + (threadIdx.x >> 6);
    int lane = threadIdx.x & 63;
    int grp = lane >> 4;
    int j16 = lane & 15;
    int head = j16 >> 2;
    int cbase = j16 * 8;

    float acc[8];
    if (first) {
#pragma unroll
        for (int t = 0; t < 8; t++) {
            float s = 0.f;
#pragma unroll
            for (int r = 0; r < N_REL_C; r++) s += bias[r * HID_C + cbase + t];
            acc[t] = s;
        }
    } else {
        float4 b0 = *(const float4*)(B + (size_t)node * HID_C + cbase);
        float4 b1 = *(const float4*)(B + (size_t)node * HID_C + cbase + 4);
        acc[0] = b0.x; acc[1] = b0.y; acc[2] = b0.z; acc[3] = b0.w;
        acc[4] = b1.x; acc[5] = b1.y; acc[6] = b1.z; acc[7] = b1.w;
    }

    for (int j = 0; j < rel_cnt; j++) {
        int r = rel_start + j;
        const int* rp = rowptrP + (size_t)r * (N_NODES_C + 1);
        const int* bs = bsums + r * NBLK_SCAN;
        const int* sp = srcids + (size_t)r * N_EDGES_C;
        const __half* Aj = A + (size_t)j * N_NODES_C * HID_C;
        const float* alj = als + (size_t)j * N_NODES_C * HEADS_C;
        float aldv = ald[(size_t)j * N_NODES_C * HEADS_C + node * HEADS_C + head];
        int s = rp[node] + bs[node >> 8];
        int e = (node == N_NODES_C - 1) ? N_EDGES_C
                                        : rp[node + 1] + bs[(node + 1) >> 8];
        float racc[8];
#pragma unroll
        for (int t = 0; t < 8; t++) racc[t] = 0.f;
        float rden = 0.f;

        union HU { uint4 u; _Float16 h[8]; };
        int i = s + grp;
        int src = (i < e) ? sp[i] : 0;
        HU rw; rw.u = *(const uint4*)(Aj + (size_t)src * HID_C + cbase);
        float lg = alj[src * HEADS_C + head];
        for (; i < e; i += 4) {
            int nsrc = (i + 4 < e) ? sp[i + 4] : 0;
            HU nrw; nrw.u = *(const uint4*)(Aj + (size_t)nsrc * HID_C + cbase);
            float nlg = alj[nsrc * HEADS_C + head];
            float v = lg + aldv;
            v = fmaxf(v, 0.2f * v);          // leaky_relu
            float ex = __expf(v);
            rden += ex;
#pragma unroll
            for (int t = 0; t < 8; t++)
                racc[t] = fmaf((float)rw.h[t], ex, racc[t]);
            src = nsrc; rw = nrw; lg = nlg;
        }
#pragma unroll
        for (int off = 16; off < 64; off <<= 1) {
            rden += __shfl_xor(rden, off);
#pragma unroll
            for (int t = 0; t < 8; t++) racc[t] += __shfl_xor(racc[t], off);
        }
        float inv = 1.f / (rden + 1e-16f);
#pragma unroll
        for (int t = 0; t < 8; t++) acc[t] = fmaf(racc[t], inv, acc[t]);
    }

    if (!last) {
        if (grp == 0) {
            float4 o0 = make_float4(acc[0], acc[1], acc[2], acc[3]);
            float4 o1 = make_float4(acc[4], acc[5], acc[6], acc[7]);
            *(float4*)(B + (size_t)node * HID_C + cbase) = o0;
            *(float4*)(B + (size_t)node * HID_C + cbase + 4) = o1;
        }
    } else {
        float ss[8];
        float sum = 0.f, sq = 0.f;
#pragma unroll
        for (int t = 0; t < 8; t++) {
            float v = acc[t] / (1.f + fabsf(acc[t]));
            ss[t] = v;
            sum += v;
            sq = fmaf(v, v, sq);
        }
#pragma unroll
        for (int off = 1; off < 16; off <<= 1) {
            sum += __shfl_xor(sum, off);
            sq += __shfl_xor(sq, off);
        }
        float mu = sum * (1.f / 128.f);
        float var = sq * (1.f / 128.f) - mu * mu;
        float inv = rsqrtf(var + 1e-5f);
        if (grp == 0) {
            float4 gv0 = *(const float4*)(g + cbase);
            float4 gv1 = *(const float4*)(g + cbase + 4);
            float4 bv0 = *(const float4*)(be + cbase);
            float4 bv1 = *(const float4*)(be + cbase + 4);
            union { uint4 u; __half2 h2[4]; } ow;
            ow.h2[0] = __float22half2_rn(make_float2(
                (ss[0] - mu) * inv * gv0.x + bv0.x, (ss[1] - mu) * inv * gv0.y + bv0.y));
            ow.h2[1] = __float22half2_rn(make_float2(
                (ss[2] - mu) * inv * gv0.z + bv0.z, (ss[3] - mu) * inv * gv0.w + bv0.w));
            ow.h2[2] = __float22half2_rn(make_float2(
                (ss[4] - mu) * inv * gv1.x + bv1.x, (ss[5] - mu) * inv * gv1.y + bv1.y));
            ow.h2[3] = __float22half2_rn(make_float2(
                (ss[6] - mu) * inv * gv1.z + bv1.z, (ss[7] - mu) * inv * gv1.w + bv1.w));
            *(uint4*)(Cbh + (size_t)node * HID_C + cbase) = ow.u;
        }
    }
}

// ================= pooling + projection =================
__device__ __forceinline__ int lower_bound_i(const int* __restrict__ a, int n, int v) {
    int lo = 0, hi = n;
    while (lo < hi) {
        int mid = (lo + hi) >> 1;
        if (a[mid] < v) lo = mid + 1; else hi = mid;
    }
    return lo;
}

__global__ __launch_bounds__(256) void pool_kernel(const __half* __restrict__ H,
                                                   const int* __restrict__ batch,
                                                   const float* __restrict__ q,
                                                   float* __restrict__ pooled) {
    int g = blockIdx.x;
    int t = threadIdx.x;
    int wave = t >> 6, lane = t & 63;
    int start = lower_bound_i(batch, N_NODES_C, g);
    int end = lower_bound_i(batch, N_NODES_C, g + 1);
    float q0 = q[lane * 2], q1 = q[lane * 2 + 1];
    float p0 = 0.f, p1 = 0.f, den = 0.f;
    for (int n = start + wave; n < end; n += 4) {
        float2 hv = __half22float2(*(const __half2*)(H + (size_t)n * HID_C + lane * 2));
        float part = hv.x * q0 + hv.y * q1;
#pragma unroll
        for (int off = 1; off < 64; off <<= 1) part += __shfl_xor(part, off);
        float exs = __expf(part);
        den += exs;
        p0 = fmaf(exs, hv.x, p0);
        p1 = fmaf(exs, hv.y, p1);
    }
    __shared__ float sp[4][HID_C];
    __shared__ float sden[4];
    sp[wave][lane * 2] = p0;
    sp[wave][lane * 2 + 1] = p1;
    if (lane == 0) sden[wave] = den;
    __syncthreads();
    if (wave == 0) {
        float a0 = sp[0][lane * 2] + sp[1][lane * 2] + sp[2][lane * 2] + sp[3][lane * 2];
        float a1 = sp[0][lane * 2 + 1] + sp[1][lane * 2 + 1] + sp[2][lane * 2 + 1] + sp[3][lane * 2 + 1];
        float d = sden[0] + sden[1] + sden[2] + sden[3];
        float w = 1.f / (d + 1e-16f);
        pooled[(size_t)g * HID_C + lane * 2] = a0 * w;
        pooled[(size_t)g * HID_C + lane * 2 + 1] = a1 * w;
    }
}

__global__ __launch_bounds__(128) void proj_kernel(const float* __restrict__ pooled,
                                                   const float* __restrict__ Wp,
                                                   const float* __restrict__ bp,
                                                   float* __restrict__ out) {
    int g = blockIdx.x, c = threadIdx.x;
    __shared__ float pl[HID_C];
    pl[c] = pooled[(size_t)g * HID_C + c];
    __syncthreads();
    float s = bp[c];
    for (int k = 0; k < HID_C; k++) s = fmaf(pl[k], Wp[k * HID_C + c], s);
    out[(size_t)g * HID_C + c] = s;
}

extern "C" void kernel_launch(void* const* d_in, const int* in_sizes, int n_in,
                              void* d_out, int out_size, void* d_ws, size_t ws_size,
                              hipStream_t stream) {
    const float* x   = (const float*)d_in[0];
    const int* ei    = (const int*)d_in[1];
    const int* batch = (const int*)d_in[2];
    const float* W1  = (const float*)d_in[3];
    const float* as1 = (const float*)d_in[4];
    const float* ad1 = (const float*)d_in[5];
    const float* b1  = (const float*)d_in[6];
    const float* W2  = (const float*)d_in[7];
    const float* as2 = (const float*)d_in[8];
    const float* ad2 = (const float*)d_in[9];
    const float* b2  = (const float*)d_in[10];
    const float* g1  = (const float*)d_in[11];
    const float* be1 = (const float*)d_in[12];
    const float* g2  = (const float*)d_in[13];
    const float* be2 = (const float*)d_in[14];
    const float* q   = (const float*)d_in[15];
    const float* Wp  = (const float*)d_in[16];
    const float* bp  = (const float*)d_in[17];
    float* out = (float*)d_out;

    // ---- workspace layout: identical to the proven round-0 kernel ----
    const size_t NH = (size_t)N_NODES_C * HID_C;
    char* w = (char*)d_ws;
    __half* xh    = (__half*)w;   w += (size_t)N_NODES_C * IN_DIM_C * 2;
    __half* Cbh   = (__half*)w;   w += NH * 2;
    __half* Wt1   = (__half*)w;   w += (size_t)N_REL_C * IN_DIM_C * HID_C * 2;
    __half* Wt2   = (__half*)w;   w += (size_t)N_REL_C * HID_C * HID_C * 2;
    float* pooled = (float*)w;    w += (size_t)N_GRAPHS_C * HID_C * 4;
    int* rowptr   = (int*)w;      w += ((size_t)N_REL_C * (N_NODES_C + 1) * 4 + 15) & ~15ull;
    int* srcids   = (int*)w;      w += (size_t)N_REL_C * N_EDGES_C * 4;
    int* cnt      = (int*)w;      w += (size_t)N_REL_C * N_NODES_C * 4;
    int* bsums    = (int*)w;      w += ((size_t)N_REL_C * NBLK_SCAN * 4 + 15) & ~15ull;

    const size_t fixed_bytes = (size_t)(w - (char*)d_ws);
    const size_t slot_bytes = NH * 2 + 2 * (size_t)N_NODES_C * HEADS_C * 4;
    int nA = 1;
    float* B = nullptr;
    {
        size_t rem = (ws_size > fixed_bytes) ? (ws_size - fixed_bytes) : 0;
        size_t k = rem / slot_bytes;
        if (k >= 6) {
            nA = 6;
        } else {
            size_t rem2 = (rem > NH * 4) ? (rem - NH * 4) : 0;
            size_t k2 = rem2 / slot_bytes;
            nA = (int)(k2 < 1 ? 1 : (k2 > 5 ? 5 : k2));
        }
    }
    float* als = (float*)w;
    float* ald = als + (size_t)nA * N_NODES_C * HEADS_C;
    __half* A  = (__half*)(ald + (size_t)nA * N_NODES_C * HEADS_C);
    if (nA < 6) B = (float*)(A + (size_t)nA * NH);
    // rank[] only live during CSR build, before A is written: alias into A slab
    int* rank = (int*)A;   // 12 MB <= 25.6 MB (first slot)

    // ---- CSR build + converts (fused first pass) ----
    hipMemsetAsync(cnt, 0, (size_t)N_REL_C * N_NODES_C * sizeof(int), stream);
    const int ehg = (N_REL_C * N_EDGES_C + 255) / 256;
    hist_rank_convert_kernel<<<ehg, 256, 0, stream>>>(ei, cnt, rank, x, xh, W1, W2, Wt1, Wt2);
    scan1_kernel<<<dim3(NBLK_SCAN, N_REL_C), 256, 0, stream>>>(cnt, rowptr, bsums);
    scan2_kernel<<<N_REL_C, 512, 0, stream>>>(bsums);
    scatter_kernel<<<ehg, 256, 0, stream>>>(ei, rowptr, bsums, rank, srcids);

    const int gemm_grid = (N_NODES_C + 63) / 64;
    const int agg_grid = N_NODES_C / 4;

    // ---- layer 1 ----
    for (int gs = 0; gs < N_REL_C; gs += nA) {
        int c2 = (N_REL_C - gs) < nA ? (N_REL_C - gs) : nA;
        gemm_mfma_kernel<IN_DIM_C><<<gemm_grid, 256, 0, stream>>>(
            xh, Wt1 + (size_t)gs * IN_DIM_C * HID_C, A,
            as1 + gs * HID_C, ad1 + gs * HID_C, als, ald, c2);
        csr_agg_kernel<<<agg_grid, 256, 0, stream>>>(
            rowptr, bsums, srcids, A, als, ald, gs, c2,
            b1, (gs == 0) ? 1 : 0, (gs + c2 == N_REL_C) ? 1 : 0,
            B, g1, be1, Cbh);
    }
    // ---- layer 2 ----
    for (int gs = 0; gs < N_REL_C; gs += nA) {
        int c2 = (N_REL_C - gs) < nA ? (N_REL_C - gs) : nA;
        gemm_mfma_kernel<HID_C><<<gemm_grid, 256, 0, stream>>>(
            Cbh, Wt2 + (size_t)gs * HID_C * HID_C, A,
            as2 + gs * HID_C, ad2 + gs * HID_C, als, ald, c2);
        csr_agg_kernel<<<agg_grid, 256, 0, stream>>>(
            rowptr, bsums, srcids, A, als, ald, gs, c2,
            b2, (gs == 0) ? 1 : 0, (gs + c2 == N_REL_C) ? 1 : 0,
            B, g2, be2, Cbh);
    }

    // ---- pooling + projection ----
    pool_kernel<<<N_GRAPHS_C, 256, 0, stream>>>(Cbh, batch, q, pooled);
    proj_kernel<<<N_GRAPHS_C, 128, 0, stream>>>(pooled, Wp, bp, out);
}

// Round 6
// 941.135 us; speedup vs baseline: 1.3140x; 1.1481x over previous
//
#include <hip/hip_runtime.h>
#include <hip/hip_bf16.h>
#include <hip/hip_fp16.h>

#define N_NODES_C 100000
#define N_EDGES_C 500000
#define N_REL_C 6
#define IN_DIM_C 64
#define HID_C 128
#define HEADS_C 4
#define CPH_C 32
#define N_GRAPHS_C 1024
#define NBLK_SCAN 391   // ceil(100000/256)

typedef _Float16 f16x8 __attribute__((ext_vector_type(8)));
typedef float f32x4 __attribute__((ext_vector_type(4)));

// ========== CSR hist+rank, fused with fp32->fp16 converts ==========
__global__ __launch_bounds__(256) void hist_rank_convert_kernel(
    const int* __restrict__ ei, int* __restrict__ cnt, int* __restrict__ rank,
    const float* __restrict__ x, __half* __restrict__ xh,
    const float* __restrict__ W1, const float* __restrict__ W2,
    __half* __restrict__ Wt1, __half* __restrict__ Wt2) {
    int i = blockIdx.x * 256 + threadIdx.x;
    // convert x (1.6M float4 groups)
    if (i < N_NODES_C * IN_DIM_C / 4) {
        float4 v = ((const float4*)x)[i];
        union { __half h[4]; uint2 u; } u;
        u.h[0] = __float2half(v.x); u.h[1] = __float2half(v.y);
        u.h[2] = __float2half(v.z); u.h[3] = __float2half(v.w);
        ((uint2*)xh)[i] = u.u;
    }
    // convert + transpose W1, W2
    if (i < N_REL_C * IN_DIM_C * HID_C) {
        int r = i / (IN_DIM_C * HID_C);
        int rem = i - r * (IN_DIM_C * HID_C);
        int k = rem / HID_C, n = rem - k * HID_C;
        Wt1[(size_t)r * HID_C * IN_DIM_C + n * IN_DIM_C + k] = __float2half(W1[i]);
    }
    if (i < N_REL_C * HID_C * HID_C) {
        int r = i / (HID_C * HID_C);
        int rem = i - r * (HID_C * HID_C);
        int k = rem / HID_C, n = rem - k * HID_C;
        Wt2[(size_t)r * HID_C * HID_C + n * HID_C + k] = __float2half(W2[i]);
    }
    // histogram + per-edge rank
    if (i < N_REL_C * N_EDGES_C) {
        int r = i / N_EDGES_C;
        int e = i - r * N_EDGES_C;
        int dst = ei[(size_t)r * 2 * N_EDGES_C + N_EDGES_C + e];
        rank[i] = atomicAdd(&cnt[r * N_NODES_C + dst], 1);
    }
}

// per-256-block exclusive scan; bsums[r][b] = block total
__global__ __launch_bounds__(256) void scan1_kernel(const int* __restrict__ cnt,
                                                    int* __restrict__ rowptr,
                                                    int* __restrict__ blocksums) {
    int r = blockIdx.y, b = blockIdx.x, t = threadIdx.x;
    int idx = b * 256 + t;
    int v = (idx < N_NODES_C) ? cnt[r * N_NODES_C + idx] : 0;
    int orig = v;
    int lane = t & 63, w = t >> 6;
#pragma unroll
    for (int off = 1; off < 64; off <<= 1) {
        int n = __shfl_up(v, off);
        if (lane >= off) v += n;
    }
    __shared__ int wt[4];
    if (lane == 63) wt[w] = v;
    __syncthreads();
    int add = 0;
    for (int i = 0; i < w; i++) add += wt[i];
    v += add;
    if (idx < N_NODES_C) rowptr[(size_t)r * (N_NODES_C + 1) + idx] = v - orig;
    if (t == 255) blocksums[r * NBLK_SCAN + b] = v;
}

// scan block sums -> exclusive prefixes (final rowptr = rowptrP + bsums[b])
__global__ __launch_bounds__(512) void scan2_kernel(int* __restrict__ blocksums) {
    int r = blockIdx.x, t = threadIdx.x;
    int v = (t < NBLK_SCAN) ? blocksums[r * NBLK_SCAN + t] : 0;
    int orig = v;
    int lane = t & 63, w = t >> 6;
#pragma unroll
    for (int off = 1; off < 64; off <<= 1) {
        int n = __shfl_up(v, off);
        if (lane >= off) v += n;
    }
    __shared__ int wt[8];
    if (lane == 63) wt[w] = v;
    __syncthreads();
    int add = 0;
    for (int i = 0; i < w; i++) add += wt[i];
    v += add;
    if (t < NBLK_SCAN) blocksums[r * NBLK_SCAN + t] = v - orig;
}

// atomic-free scatter; final rowptr computed inline
__global__ __launch_bounds__(256) void scatter_kernel(const int* __restrict__ ei,
                                                      const int* __restrict__ rowptrP,
                                                      const int* __restrict__ bsums,
                                                      const int* __restrict__ rank,
                                                      int* __restrict__ srcids) {
    int i = blockIdx.x * 256 + threadIdx.x;
    if (i >= N_REL_C * N_EDGES_C) return;
    int r = i / N_EDGES_C;
    int e = i - r * N_EDGES_C;
    int src = ei[(size_t)r * 2 * N_EDGES_C + e];
    int dst = ei[(size_t)r * 2 * N_EDGES_C + N_EDGES_C + e];
    int base = rowptrP[(size_t)r * (N_NODES_C + 1) + dst] + bsums[r * NBLK_SCAN + (dst >> 8)];
    srcids[(size_t)r * N_EDGES_C + base + rank[i]] = src;
}

// ================= fp16 MFMA GEMM + attn-logit epilogue =================
// grid.y = relation slot (full parallelism). New vs round-0:
//  - Wt slot staged to LDS once per block (kills the all-blocks-same-L2-lines
//    hotspot; B fragments via ds_read_b128, +8-half row pad => 2-way only)
//  - B-LDS reused as the transpose buffer after a barrier (no extra LDS)
//  - attn logits assembled in LDS and stored as full float4 rows (no 4B RMW)
template <int K>
__global__ __launch_bounds__(256) void gemm_mfma_kernel(
    const __half* __restrict__ Xh, const __half* __restrict__ Wtbase,
    __half* __restrict__ Hbase,
    const float* __restrict__ asbase, const float* __restrict__ adbase,
    float* __restrict__ alsbase, float* __restrict__ aldbase) {
    __shared__ _Float16 Bsh[128][K + 8];      // K=64: 18.4KB, K=128: 34.8KB
    __shared__ float lgb[4][2][16][4];        // per-wave logit assembly (2KB)
    const int slot = blockIdx.y;
    const __half* Wt = Wtbase + (size_t)slot * HID_C * K;
    __half* H = Hbase + (size_t)slot * N_NODES_C * HID_C;
    const int tid = threadIdx.x;
    const int wave = tid >> 6, lane = tid & 63;
    const int m = lane & 15, quad = lane >> 4;

    // ---- cooperative B staging: Wt[n][k] -> Bsh[n][k] (coalesced 16B chunks) ----
    constexpr int CPR = K / 8;                 // 16B chunks per row
    constexpr int NCHUNK = 128 * CPR;
#pragma unroll
    for (int j = 0; j < NCHUNK / 256; j++) {
        int chunk = tid + j * 256;
        int n = chunk / CPR;
        int kc = (chunk - n * CPR) * 8;
        *(uint4*)&Bsh[n][kc] = *(const uint4*)(Wt + (size_t)n * K + kc);
    }
    __syncthreads();

    const int r0 = blockIdx.x * 64 + wave * 16;
    int arow = r0 + m;
    if (arow > N_NODES_C - 1) arow = N_NODES_C - 1;
    const __half* ap = Xh + (size_t)arow * K + quad * 8;

    f32x4 acc[8];
#pragma unroll
    for (int t = 0; t < 8; t++) acc[t] = (f32x4){0.f, 0.f, 0.f, 0.f};

#pragma unroll
    for (int kc = 0; kc < K; kc += 32) {
        f16x8 a = *(const f16x8*)(ap + kc);
#pragma unroll
        for (int t = 0; t < 8; t++) {
            f16x8 b = *(const f16x8*)&Bsh[t * 16 + m][kc + quad * 8];
            acc[t] = __builtin_amdgcn_mfma_f32_16x16x32_f16(a, b, acc[t], 0, 0, 0);
        }
    }
    __syncthreads();   // B done everywhere; Bsh is now the transpose scratch

    // ---- transpose C-layout -> row-major via per-wave LDS region ----
    _Float16* trp = &Bsh[0][0] + wave * (16 * 136);   // 16 rows x 136 halves
#pragma unroll
    for (int t = 0; t < 8; t++)
#pragma unroll
        for (int i = 0; i < 4; i++)
            trp[(quad * 4 + i) * 136 + t * 16 + m] = (_Float16)acc[t][i];
#pragma unroll
    for (int p = 0; p < 4; p++) {
        int idx = p * 512 + lane * 8;
        int row = idx >> 7;
        int col = idx & 127;
        int R = r0 + row;
        if (R < N_NODES_C)
            *(uint4*)(H + (size_t)R * HID_C + col) = *(const uint4*)&trp[row * 136 + col];
    }

    // ---- attention logits from fp32 accumulators ----
    const float* a_s = asbase + slot * HID_C;
    const float* a_d = adbase + slot * HID_C;
    float* als = alsbase + (size_t)slot * N_NODES_C * HEADS_C;
    float* ald = aldbase + (size_t)slot * N_NODES_C * HEADS_C;
    float ps[4][4], pd[4][4];
#pragma unroll
    for (int h = 0; h < 4; h++) {
        float as0 = a_s[h * 32 + m], as1 = a_s[h * 32 + 16 + m];
        float ad0 = a_d[h * 32 + m], ad1 = a_d[h * 32 + 16 + m];
#pragma unroll
        for (int i = 0; i < 4; i++) {
            ps[h][i] = acc[2 * h][i] * as0 + acc[2 * h + 1][i] * as1;
            pd[h][i] = acc[2 * h][i] * ad0 + acc[2 * h + 1][i] * ad1;
        }
    }
#pragma unroll
    for (int off = 1; off < 16; off <<= 1) {
#pragma unroll
        for (int h = 0; h < 4; h++)
#pragma unroll
            for (int i = 0; i < 4; i++) {
                ps[h][i] += __shfl_xor(ps[h][i], off);
                pd[h][i] += __shfl_xor(pd[h][i], off);
            }
    }
    // assemble rows in LDS (same-wave write->read ordering), store full float4
#pragma unroll
    for (int h = 0; h < 4; h++) {
        if (m == h) {
#pragma unroll
            for (int i = 0; i < 4; i++) {
                lgb[wave][0][quad * 4 + i][h] = ps[h][i];
                lgb[wave][1][quad * 4 + i][h] = pd[h][i];
            }
        }
    }
    {
        int row = lane & 15;
        int which = lane >> 4;   // 0:als 1:ald 2,3:idle
        if (which < 2) {
            int R = r0 + row;
            if (R < N_NODES_C) {
                float4 v = *(const float4*)&lgb[wave][which][row][0];
                float* dst = which ? ald : als;
                *(float4*)(dst + (size_t)R * HEADS_C) = v;
            }
        }
    }
}

// ========== fused multi-relation aggregate + bias + softsign + LN ==========
// (exact round-0 body)
__global__ __launch_bounds__(256) void csr_agg_kernel(
    const int* __restrict__ rowptrP, const int* __restrict__ bsums,
    const int* __restrict__ srcids,
    const __half* __restrict__ A, const float* __restrict__ als,
    const float* __restrict__ ald, int rel_start, int rel_cnt,
    const float* __restrict__ bias, int first, int last,
    float* __restrict__ B,
    const float* __restrict__ g, const float* __restrict__ be,
    __half* __restrict__ Cbh) {
    int node = blockIdx.x * 4 + (threadIdx.x >> 6);
    int lane = threadIdx.x & 63;
    int grp = lane >> 4;
    int j16 = lane & 15;
    int head = j16 >> 2;
    int cbase = j16 * 8;

    float acc[8];
    if (first) {
#pragma unroll
        for (int t = 0; t < 8; t++) {
            float s = 0.f;
#pragma unroll
            for (int r = 0; r < N_REL_C; r++) s += bias[r * HID_C + cbase + t];
            acc[t] = s;
        }
    } else {
        float4 b0 = *(const float4*)(B + (size_t)node * HID_C + cbase);
        float4 b1 = *(const float4*)(B + (size_t)node * HID_C + cbase + 4);
        acc[0] = b0.x; acc[1] = b0.y; acc[2] = b0.z; acc[3] = b0.w;
        acc[4] = b1.x; acc[5] = b1.y; acc[6] = b1.z; acc[7] = b1.w;
    }

    for (int j = 0; j < rel_cnt; j++) {
        int r = rel_start + j;
        const int* rp = rowptrP + (size_t)r * (N_NODES_C + 1);
        const int* bs = bsums + r * NBLK_SCAN;
        const int* sp = srcids + (size_t)r * N_EDGES_C;
        const __half* Aj = A + (size_t)j * N_NODES_C * HID_C;
        const float* alj = als + (size_t)j * N_NODES_C * HEADS_C;
        float aldv = ald[(size_t)j * N_NODES_C * HEADS_C + node * HEADS_C + head];
        int s = rp[node] + bs[node >> 8];
        int e = (node == N_NODES_C - 1) ? N_EDGES_C
                                        : rp[node + 1] + bs[(node + 1) >> 8];
        float racc[8];
#pragma unroll
        for (int t = 0; t < 8; t++) racc[t] = 0.f;
        float rden = 0.f;

        union HU { uint4 u; _Float16 h[8]; };
        int i = s + grp;
        int src = (i < e) ? sp[i] : 0;
        HU rw; rw.u = *(const uint4*)(Aj + (size_t)src * HID_C + cbase);
        float lg = alj[src * HEADS_C + head];
        for (; i < e; i += 4) {
            int nsrc = (i + 4 < e) ? sp[i + 4] : 0;
            HU nrw; nrw.u = *(const uint4*)(Aj + (size_t)nsrc * HID_C + cbase);
            float nlg = alj[nsrc * HEADS_C + head];
            float v = lg + aldv;
            v = fmaxf(v, 0.2f * v);          // leaky_relu
            float ex = __expf(v);
            rden += ex;
#pragma unroll
            for (int t = 0; t < 8; t++)
                racc[t] = fmaf((float)rw.h[t], ex, racc[t]);
            src = nsrc; rw = nrw; lg = nlg;
        }
#pragma unroll
        for (int off = 16; off < 64; off <<= 1) {
            rden += __shfl_xor(rden, off);
#pragma unroll
            for (int t = 0; t < 8; t++) racc[t] += __shfl_xor(racc[t], off);
        }
        float inv = 1.f / (rden + 1e-16f);
#pragma unroll
        for (int t = 0; t < 8; t++) acc[t] = fmaf(racc[t], inv, acc[t]);
    }

    if (!last) {
        if (grp == 0) {
            float4 o0 = make_float4(acc[0], acc[1], acc[2], acc[3]);
            float4 o1 = make_float4(acc[4], acc[5], acc[6], acc[7]);
            *(float4*)(B + (size_t)node * HID_C + cbase) = o0;
            *(float4*)(B + (size_t)node * HID_C + cbase + 4) = o1;
        }
    } else {
        float ss[8];
        float sum = 0.f, sq = 0.f;
#pragma unroll
        for (int t = 0; t < 8; t++) {
            float v = acc[t] / (1.f + fabsf(acc[t]));
            ss[t] = v;
            sum += v;
            sq = fmaf(v, v, sq);
        }
#pragma unroll
        for (int off = 1; off < 16; off <<= 1) {
            sum += __shfl_xor(sum, off);
            sq += __shfl_xor(sq, off);
        }
        float mu = sum * (1.f / 128.f);
        float var = sq * (1.f / 128.f) - mu * mu;
        float inv = rsqrtf(var + 1e-5f);
        if (grp == 0) {
            float4 gv0 = *(const float4*)(g + cbase);
            float4 gv1 = *(const float4*)(g + cbase + 4);
            float4 bv0 = *(const float4*)(be + cbase);
            float4 bv1 = *(const float4*)(be + cbase + 4);
            union { uint4 u; __half2 h2[4]; } ow;
            ow.h2[0] = __float22half2_rn(make_float2(
                (ss[0] - mu) * inv * gv0.x + bv0.x, (ss[1] - mu) * inv * gv0.y + bv0.y));
            ow.h2[1] = __float22half2_rn(make_float2(
                (ss[2] - mu) * inv * gv0.z + bv0.z, (ss[3] - mu) * inv * gv0.w + bv0.w));
            ow.h2[2] = __float22half2_rn(make_float2(
                (ss[4] - mu) * inv * gv1.x + bv1.x, (ss[5] - mu) * inv * gv1.y + bv1.y));
            ow.h2[3] = __float22half2_rn(make_float2(
                (ss[6] - mu) * inv * gv1.z + bv1.z, (ss[7] - mu) * inv * gv1.w + bv1.w));
            *(uint4*)(Cbh + (size_t)node * HID_C + cbase) = ow.u;
        }
    }
}

// ================= pooling + projection =================
__device__ __forceinline__ int lower_bound_i(const int* __restrict__ a, int n, int v) {
    int lo = 0, hi = n;
    while (lo < hi) {
        int mid = (lo + hi) >> 1;
        if (a[mid] < v) lo = mid + 1; else hi = mid;
    }
    return lo;
}

__global__ __launch_bounds__(256) void pool_kernel(const __half* __restrict__ H,
                                                   const int* __restrict__ batch,
                                                   const float* __restrict__ q,
                                                   float* __restrict__ pooled) {
    int g = blockIdx.x;
    int t = threadIdx.x;
    int wave = t >> 6, lane = t & 63;
    int start = lower_bound_i(batch, N_NODES_C, g);
    int end = lower_bound_i(batch, N_NODES_C, g + 1);
    float q0 = q[lane * 2], q1 = q[lane * 2 + 1];
    float p0 = 0.f, p1 = 0.f, den = 0.f;
    for (int n = start + wave; n < end; n += 4) {
        float2 hv = __half22float2(*(const __half2*)(H + (size_t)n * HID_C + lane * 2));
        float part = hv.x * q0 + hv.y * q1;
#pragma unroll
        for (int off = 1; off < 64; off <<= 1) part += __shfl_xor(part, off);
        float exs = __expf(part);
        den += exs;
        p0 = fmaf(exs, hv.x, p0);
        p1 = fmaf(exs, hv.y, p1);
    }
    __shared__ float sp[4][HID_C];
    __shared__ float sden[4];
    sp[wave][lane * 2] = p0;
    sp[wave][lane * 2 + 1] = p1;
    if (lane == 0) sden[wave] = den;
    __syncthreads();
    if (wave == 0) {
        float a0 = sp[0][lane * 2] + sp[1][lane * 2] + sp[2][lane * 2] + sp[3][lane * 2];
        float a1 = sp[0][lane * 2 + 1] + sp[1][lane * 2 + 1] + sp[2][lane * 2 + 1] + sp[3][lane * 2 + 1];
        float d = sden[0] + sden[1] + sden[2] + sden[3];
        float w = 1.f / (d + 1e-16f);
        pooled[(size_t)g * HID_C + lane * 2] = a0 * w;
        pooled[(size_t)g * HID_C + lane * 2 + 1] = a1 * w;
    }
}

__global__ __launch_bounds__(128) void proj_kernel(const float* __restrict__ pooled,
                                                   const float* __restrict__ Wp,
                                                   const float* __restrict__ bp,
                                                   float* __restrict__ out) {
    int g = blockIdx.x, c = threadIdx.x;
    __shared__ float pl[HID_C];
    pl[c] = pooled[(size_t)g * HID_C + c];
    __syncthreads();
    float s = bp[c];
    for (int k = 0; k < HID_C; k++) s = fmaf(pl[k], Wp[k * HID_C + c], s);
    out[(size_t)g * HID_C + c] = s;
}

extern "C" void kernel_launch(void* const* d_in, const int* in_sizes, int n_in,
                              void* d_out, int out_size, void* d_ws, size_t ws_size,
                              hipStream_t stream) {
    const float* x   = (const float*)d_in[0];
    const int* ei    = (const int*)d_in[1];
    const int* batch = (const int*)d_in[2];
    const float* W1  = (const float*)d_in[3];
    const float* as1 = (const float*)d_in[4];
    const float* ad1 = (const float*)d_in[5];
    const float* b1  = (const float*)d_in[6];
    const float* W2  = (const float*)d_in[7];
    const float* as2 = (const float*)d_in[8];
    const float* ad2 = (const float*)d_in[9];
    const float* b2  = (const float*)d_in[10];
    const float* g1  = (const float*)d_in[11];
    const float* be1 = (const float*)d_in[12];
    const float* g2  = (const float*)d_in[13];
    const float* be2 = (const float*)d_in[14];
    const float* q   = (const float*)d_in[15];
    const float* Wp  = (const float*)d_in[16];
    const float* bp  = (const float*)d_in[17];
    float* out = (float*)d_out;

    // ---- workspace layout: identical to the proven round-0 kernel ----
    const size_t NH = (size_t)N_NODES_C * HID_C;
    char* w = (char*)d_ws;
    __half* xh    = (__half*)w;   w += (size_t)N_NODES_C * IN_DIM_C * 2;
    __half* Cbh   = (__half*)w;   w += NH * 2;
    __half* Wt1   = (__half*)w;   w += (size_t)N_REL_C * IN_DIM_C * HID_C * 2;
    __half* Wt2   = (__half*)w;   w += (size_t)N_REL_C * HID_C * HID_C * 2;
    float* pooled = (float*)w;    w += (size_t)N_GRAPHS_C * HID_C * 4;
    int* rowptr   = (int*)w;      w += ((size_t)N_REL_C * (N_NODES_C + 1) * 4 + 15) & ~15ull;
    int* srcids   = (int*)w;      w += (size_t)N_REL_C * N_EDGES_C * 4;
    int* cnt      = (int*)w;      w += (size_t)N_REL_C * N_NODES_C * 4;
    int* bsums    = (int*)w;      w += ((size_t)N_REL_C * NBLK_SCAN * 4 + 15) & ~15ull;

    const size_t fixed_bytes = (size_t)(w - (char*)d_ws);
    const size_t slot_bytes = NH * 2 + 2 * (size_t)N_NODES_C * HEADS_C * 4;
    int nA = 1;
    float* B = nullptr;
    {
        size_t rem = (ws_size > fixed_bytes) ? (ws_size - fixed_bytes) : 0;
        size_t k = rem / slot_bytes;
        if (k >= 6) {
            nA = 6;
        } else {
            size_t rem2 = (rem > NH * 4) ? (rem - NH * 4) : 0;
            size_t k2 = rem2 / slot_bytes;
            nA = (int)(k2 < 1 ? 1 : (k2 > 5 ? 5 : k2));
        }
    }
    float* als = (float*)w;
    float* ald = als + (size_t)nA * N_NODES_C * HEADS_C;
    __half* A  = (__half*)(ald + (size_t)nA * N_NODES_C * HEADS_C);
    if (nA < 6) B = (float*)(A + (size_t)nA * NH);
    // rank[] only live during CSR build, before A is written: alias into A slab
    int* rank = (int*)A;   // 12 MB <= 25.6 MB (first slot)

    // ---- CSR build + converts (fused first pass) ----
    hipMemsetAsync(cnt, 0, (size_t)N_REL_C * N_NODES_C * sizeof(int), stream);
    const int ehg = (N_REL_C * N_EDGES_C + 255) / 256;
    hist_rank_convert_kernel<<<ehg, 256, 0, stream>>>(ei, cnt, rank, x, xh, W1, W2, Wt1, Wt2);
    scan1_kernel<<<dim3(NBLK_SCAN, N_REL_C), 256, 0, stream>>>(cnt, rowptr, bsums);
    scan2_kernel<<<N_REL_C, 512, 0, stream>>>(bsums);
    scatter_kernel<<<ehg, 256, 0, stream>>>(ei, rowptr, bsums, rank, srcids);

    const int gemm_grid = (N_NODES_C + 63) / 64;
    const int agg_grid = N_NODES_C / 4;

    // ---- layer 1 ----
    for (int gs = 0; gs < N_REL_C; gs += nA) {
        int c2 = (N_REL_C - gs) < nA ? (N_REL_C - gs) : nA;
        gemm_mfma_kernel<IN_DIM_C><<<dim3(gemm_grid, c2), 256, 0, stream>>>(
            xh, Wt1 + (size_t)gs * IN_DIM_C * HID_C, A,
            as1 + gs * HID_C, ad1 + gs * HID_C, als, ald);
        csr_agg_kernel<<<agg_grid, 256, 0, stream>>>(
            rowptr, bsums, srcids, A, als, ald, gs, c2,
            b1, (gs == 0) ? 1 : 0, (gs + c2 == N_REL_C) ? 1 : 0,
            B, g1, be1, Cbh);
    }
    // ---- layer 2 ----
    for (int gs = 0; gs < N_REL_C; gs += nA) {
        int c2 = (N_REL_C - gs) < nA ? (N_REL_C - gs) : nA;
        gemm_mfma_kernel<HID_C><<<dim3(gemm_grid, c2), 256, 0, stream>>>(
            Cbh, Wt2 + (size_t)gs * HID_C * HID_C, A,
            as2 + gs * HID_C, ad2 + gs * HID_C, als, ald);
        csr_agg_kernel<<<agg_grid, 256, 0, stream>>>(
            rowptr, bsums, srcids, A, als, ald, gs, c2,
            b2, (gs == 0) ? 1 : 0, (gs + c2 == N_REL_C) ? 1 : 0,
            B, g2, be2, Cbh);
    }

    // ---- pooling + projection ----
    pool_kernel<<<N_GRAPHS_C, 256, 0, stream>>>(Cbh, batch, q, pooled);
    proj_kernel<<<N_GRAPHS_C, 128, 0, stream>>>(pooled, Wp, bp, out);
}